// Round 7
// baseline (848.080 us; speedup 1.0000x reference)
//
#include <hip/hip_runtime.h>
#include <hip/hip_cooperative_groups.h>
#include <math.h>

namespace cg = cooperative_groups;

#define NT 16384
#define DM 2048
#define NE 64
#define TOPK 8
#define LTAX 0.04f
#define HYST 0.1f
#define ALPHA 0.7f

typedef unsigned int u32;
typedef unsigned short u16;
typedef __attribute__((ext_vector_type(8))) short bf16x8;
typedef __attribute__((ext_vector_type(4))) float f32x4;

__device__ __forceinline__ float warp4_sum(float v) {
  v += __shfl_xor(v, 1); v += __shfl_xor(v, 2); return v;
}
__device__ __forceinline__ float warp4_max(float v) {
  v = fmaxf(v, __shfl_xor(v, 1)); v = fmaxf(v, __shfl_xor(v, 2)); return v;
}
__device__ __forceinline__ u16 f2bf(float f) {   // RNE f32->bf16
  u32 u = __float_as_uint(f);
  return (u16)((u + 0x7fffu + ((u >> 16) & 1u)) >> 16);
}
__device__ __forceinline__ float bf2f(u16 h) { return __uint_as_float(((u32)h) << 16); }

// 3-way split: a = hi + mid + lo + eps, |eps| <= 2^-24 |a| (full f32 mantissa).
__device__ __forceinline__ void split3(float a, short& h, short& m, short& l) {
  u16 hh = f2bf(a);  float r1 = a - bf2f(hh);     // exact (Sterbenz)
  u16 mm = f2bf(r1); float r2 = r1 - bf2f(mm);    // exact
  h = (short)hh; m = (short)mm; l = (short)f2bf(r2);
}

// ---------------- K0: W -> bf16 hi/mid/lo ----------------------------------
__global__ void k_wsplit3(const float* __restrict__ W, u16* __restrict__ Wh,
                          u16* __restrict__ Wm, u16* __restrict__ Wl) {
  int idx = (blockIdx.x * 256 + threadIdx.x) * 4;
  float4 v = *(const float4*)(W + idx);
  short h[4], m[4], l[4];
  split3(v.x, h[0], m[0], l[0]);
  split3(v.y, h[1], m[1], l[1]);
  split3(v.z, h[2], m[2], l[2]);
  split3(v.w, h[3], m[3], l[3]);
  *(ushort4*)(Wh + idx) = make_ushort4((u16)h[0], (u16)h[1], (u16)h[2], (u16)h[3]);
  *(ushort4*)(Wm + idx) = make_ushort4((u16)m[0], (u16)m[1], (u16)m[2], (u16)m[3]);
  *(ushort4*)(Wl + idx) = make_ushort4((u16)l[0], (u16)l[1], (u16)l[2], (u16)l[3]);
}

// ---------------- K1: MFMA GEMM, split-K=2, f64 partials --------------------
// bid = tile*2 + ks. 64 tokens/tile, K-slice of 1024 (32 chunks of 32).
// accA(hh) + accB(cross terms) flushed to f64 every 8 chunks -> error ~1e-8.
__launch_bounds__(256, 2)
__global__ void k_gemm(const float* __restrict__ x, const u16* __restrict__ Whg,
                       const u16* __restrict__ Wmg, const u16* __restrict__ Wlg,
                       double* __restrict__ Lpart) {
  __shared__ __align__(16) u16 XS[30720];   // 6 arrays x 2 buf x [64][40]
  const int tid = threadIdx.x;
  const int bid = blockIdx.x;
  const int tile = bid >> 1, ks = bid & 1;
  const int row0 = tile * 64;
  const int k0 = ks * 1024;
  const int lane = tid & 63, w = tid >> 6, l15 = lane & 15, l4 = lane >> 4;
  const int srow = tid >> 2, c8 = (tid & 3) * 8;
  const int stoff = srow * 40 + c8;

  f32x4 accA[4], accB[4];
  double accD[4][4];
#pragma unroll
  for (int eb = 0; eb < 4; eb++) {
    accA[eb] = (f32x4)0.f; accB[eb] = (f32x4)0.f;
#pragma unroll
    for (int r = 0; r < 4; r++) accD[eb][r] = 0.0;
  }

  float4 xq0, xq1;
  uint4 whv, wmv, wlv;
  const float* xrowp = x + (size_t)(row0 + srow) * DM + k0 + c8;
  const u16* whp = Whg + srow * DM + k0 + c8;
  const u16* wmp = Wmg + srow * DM + k0 + c8;
  const u16* wlp = Wlg + srow * DM + k0 + c8;

#define LOADCH(KC) { \
    xq0 = *(const float4*)(xrowp + (KC)); \
    xq1 = *(const float4*)(xrowp + (KC) + 4); \
    whv = *(const uint4*)(whp + (KC)); \
    wmv = *(const uint4*)(wmp + (KC)); \
    wlv = *(const uint4*)(wlp + (KC)); }

#define WRITECH(B) { \
    short ha[8], ma[8], la[8]; \
    split3(xq0.x, ha[0], ma[0], la[0]); \
    split3(xq0.y, ha[1], ma[1], la[1]); \
    split3(xq0.z, ha[2], ma[2], la[2]); \
    split3(xq0.w, ha[3], ma[3], la[3]); \
    split3(xq1.x, ha[4], ma[4], la[4]); \
    split3(xq1.y, ha[5], ma[5], la[5]); \
    split3(xq1.z, ha[6], ma[6], la[6]); \
    split3(xq1.w, ha[7], ma[7], la[7]); \
    bf16x8 xh8, xm8, xl8; \
    _Pragma("unroll") \
    for (int z = 0; z < 8; z++) { xh8[z] = ha[z]; xm8[z] = ma[z]; xl8[z] = la[z]; } \
    *(bf16x8*)(XS + 0     + (B) * 2560 + stoff) = xh8; \
    *(bf16x8*)(XS + 5120  + (B) * 2560 + stoff) = xm8; \
    *(bf16x8*)(XS + 10240 + (B) * 2560 + stoff) = xl8; \
    *(uint4*)(XS + 15360 + (B) * 2560 + stoff) = whv; \
    *(uint4*)(XS + 20480 + (B) * 2560 + stoff) = wmv; \
    *(uint4*)(XS + 25600 + (B) * 2560 + stoff) = wlv; }

#define COMPUTECH(B) { \
    const int ar = (w * 16 + l15) * 40 + l4 * 8; \
    bf16x8 ah = *(const bf16x8*)(XS + 0     + (B) * 2560 + ar); \
    bf16x8 am = *(const bf16x8*)(XS + 5120  + (B) * 2560 + ar); \
    bf16x8 al = *(const bf16x8*)(XS + 10240 + (B) * 2560 + ar); \
    _Pragma("unroll") \
    for (int eb = 0; eb < 4; eb++) { \
      const int br = (eb * 16 + l15) * 40 + l4 * 8; \
      bf16x8 bh = *(const bf16x8*)(XS + 15360 + (B) * 2560 + br); \
      bf16x8 bm = *(const bf16x8*)(XS + 20480 + (B) * 2560 + br); \
      bf16x8 bl = *(const bf16x8*)(XS + 25600 + (B) * 2560 + br); \
      accA[eb] = __builtin_amdgcn_mfma_f32_16x16x32_bf16(ah, bh, accA[eb], 0, 0, 0); \
      accB[eb] = __builtin_amdgcn_mfma_f32_16x16x32_bf16(ah, bm, accB[eb], 0, 0, 0); \
      accB[eb] = __builtin_amdgcn_mfma_f32_16x16x32_bf16(am, bh, accB[eb], 0, 0, 0); \
      accB[eb] = __builtin_amdgcn_mfma_f32_16x16x32_bf16(am, bm, accB[eb], 0, 0, 0); \
      accB[eb] = __builtin_amdgcn_mfma_f32_16x16x32_bf16(ah, bl, accB[eb], 0, 0, 0); \
      accB[eb] = __builtin_amdgcn_mfma_f32_16x16x32_bf16(al, bh, accB[eb], 0, 0, 0); \
    } }

  LOADCH(0);
  WRITECH(0);
  __syncthreads();
#pragma unroll 1
  for (int t = 0; t < 32; t++) {
    if (t < 31) LOADCH((t + 1) * 32);
    COMPUTECH(t & 1);
    if ((t & 7) == 7) {               // drain f32 accs into f64 (K=256 slices)
#pragma unroll
      for (int eb = 0; eb < 4; eb++) {
#pragma unroll
        for (int r = 0; r < 4; r++)
          accD[eb][r] += (double)accA[eb][r] + (double)accB[eb][r];
        accA[eb] = (f32x4)0.f; accB[eb] = (f32x4)0.f;
      }
    }
    if (t < 31) WRITECH((t + 1) & 1);
    __syncthreads();
  }

  // C/D layout: col=lane&15 (expert), row=(lane>>4)*4+reg (token) [verified]
  double* outp = Lpart + (size_t)ks * NT * NE;
#pragma unroll
  for (int eb = 0; eb < 4; eb++)
#pragma unroll
    for (int r = 0; r < 4; r++) {
      int trow = w * 16 + l4 * 4 + r;
      outp[(size_t)(row0 + trow) * NE + eb * 16 + l15] = accD[eb][r];
    }
}

// ---------------- K2: cooperative tail (grid=256 x 256) ---------------------
__launch_bounds__(256, 1)
__global__ void k_router(const double* __restrict__ Lpart, const float* __restrict__ b,
                         const float* __restrict__ pp, const void* __restrict__ pmask,
                         float* __restrict__ Cpart, float* __restrict__ Cm,
                         float* __restrict__ colA, float* __restrict__ colB,
                         float* __restrict__ out) {
  cg::grid_group gg = cg::this_grid();
  __shared__ __align__(16) unsigned char SMEM[37120];
  __shared__ int s_cnt[256];
  __shared__ int s_flag;

  float* SMEMf = (float*)SMEM;
  float* ms = SMEMf;                        // [64][68]  (4352)
  float* Cs = SMEMf + 4352;                 // [64][64]  (4096)
  float* cred = SMEMf + 8448;               // [4][64]   (256)
  float* fac = SMEMf + 8704;                // [64]      (64)
  double* redd = (double*)(SMEMf + 8768);   // [256] doubles (512 f)

  const int tid = threadIdx.x;
  const int bid = blockIdx.x;
  const int lane = tid & 63;
  const int w = tid >> 6;
  const int row0 = bid * 64;

  // ---- prev_mask format detect (first 4096 bytes; deterministic) ----
  // u8 -> 512 nonzero bytes, f32 -> 256, i32 -> 128.
  {
    uint4 v = ((const uint4*)pmask)[tid];
    int c = 0; u32 ww;
    ww = v.x; c += ((ww & 0xffu) != 0) + ((ww & 0xff00u) != 0) + ((ww & 0xff0000u) != 0) + ((ww & 0xff000000u) != 0);
    ww = v.y; c += ((ww & 0xffu) != 0) + ((ww & 0xff00u) != 0) + ((ww & 0xff0000u) != 0) + ((ww & 0xff000000u) != 0);
    ww = v.z; c += ((ww & 0xffu) != 0) + ((ww & 0xff00u) != 0) + ((ww & 0xff0000u) != 0) + ((ww & 0xff000000u) != 0);
    ww = v.w; c += ((ww & 0xffu) != 0) + ((ww & 0xff00u) != 0) + ((ww & 0xff0000u) != 0) + ((ww & 0xff000000u) != 0);
    s_cnt[tid] = c;
    __syncthreads();
    for (int s = 128; s; s >>= 1) { if (tid < s) s_cnt[tid] += s_cnt[tid + s]; __syncthreads(); }
    if (tid == 0) { int n = s_cnt[0]; s_flag = (n > 384) ? 0 : ((n > 192) ? 2 : 1); }
    __syncthreads();
  }

  // ---- logits from f64 partials + bias; center; softmax #1 ----
  const int tg = tid >> 2, q = tid & 3;
  const int row = row0 + tg;
  float l[16], m[16];
  {
    const double* p0 = Lpart + (size_t)row * NE + q * 16;
    const double* p1 = p0 + (size_t)NT * NE;
#pragma unroll
    for (int i = 0; i < 4; i++) {
      float4 bv = *(const float4*)(b + q * 16 + i * 4);
      l[i * 4 + 0] = (float)(p0[i * 4 + 0] + p1[i * 4 + 0]) + bv.x;
      l[i * 4 + 1] = (float)(p0[i * 4 + 1] + p1[i * 4 + 1]) + bv.y;
      l[i * 4 + 2] = (float)(p0[i * 4 + 2] + p1[i * 4 + 2]) + bv.z;
      l[i * 4 + 3] = (float)(p0[i * 4 + 3] + p1[i * 4 + 3]) + bv.w;
    }
    float s = 0.f;
#pragma unroll
    for (int j = 0; j < 16; j++) s += l[j];
    s = warp4_sum(s);
    const float mean = s * (1.0f / 64.0f);
    float mx = -1e30f;
#pragma unroll
    for (int j = 0; j < 16; j++) { l[j] -= mean; mx = fmaxf(mx, l[j]); }
    mx = warp4_max(mx);
    float ps = 0.f;
#pragma unroll
    for (int j = 0; j < 16; j++) { m[j] = expf(l[j] - mx); ps += m[j]; }
    ps = warp4_sum(ps);
    const float inv = 1.0f / ps;
#pragma unroll
    for (int j = 0; j < 16; j++) m[j] *= inv;
#pragma unroll
    for (int i = 0; i < 4; i++)
      *(float4*)(ms + tg * 68 + q * 16 + i * 4) =
          make_float4(m[i * 4], m[i * 4 + 1], m[i * 4 + 2], m[i * 4 + 3]);
  }
  __syncthreads();

  // ---- gram partial ----
  {
    const int gi0 = (tid >> 4) * 4;
    const int gj0 = (tid & 15) * 4;
    float ga[4][4];
#pragma unroll
    for (int a = 0; a < 4; a++)
#pragma unroll
      for (int c = 0; c < 4; c++) ga[a][c] = 0.f;
    for (int t = 0; t < 64; t++) {
      float4 a = *(const float4*)(ms + t * 68 + gi0);
      float4 bb = *(const float4*)(ms + t * 68 + gj0);
      ga[0][0] = fmaf(a.x, bb.x, ga[0][0]); ga[0][1] = fmaf(a.x, bb.y, ga[0][1]);
      ga[0][2] = fmaf(a.x, bb.z, ga[0][2]); ga[0][3] = fmaf(a.x, bb.w, ga[0][3]);
      ga[1][0] = fmaf(a.y, bb.x, ga[1][0]); ga[1][1] = fmaf(a.y, bb.y, ga[1][1]);
      ga[1][2] = fmaf(a.y, bb.z, ga[1][2]); ga[1][3] = fmaf(a.y, bb.w, ga[1][3]);
      ga[2][0] = fmaf(a.z, bb.x, ga[2][0]); ga[2][1] = fmaf(a.z, bb.y, ga[2][1]);
      ga[2][2] = fmaf(a.z, bb.z, ga[2][2]); ga[2][3] = fmaf(a.z, bb.w, ga[2][3]);
      ga[3][0] = fmaf(a.w, bb.x, ga[3][0]); ga[3][1] = fmaf(a.w, bb.y, ga[3][1]);
      ga[3][2] = fmaf(a.w, bb.z, ga[3][2]); ga[3][3] = fmaf(a.w, bb.w, ga[3][3]);
    }
    float* op = Cpart + (size_t)bid * 4096;
#pragma unroll
    for (int ii = 0; ii < 4; ii++)
      *(float4*)(op + (gi0 + ii) * 64 + gj0) =
          make_float4(ga[ii][0], ga[ii][1], ga[ii][2], ga[ii][3]);
  }
  __threadfence();
  gg.sync();

  // ---- gram reduce (f64, fixed order) ----
  {
    const int ei = tid >> 4, gz = tid & 15;
    const int eidx = bid * 16 + ei;
    double s = 0.0;
    for (int z2 = 0; z2 < 16; z2++) s += (double)Cpart[(size_t)(gz * 16 + z2) * 4096 + eidx];
    redd[tid] = s;
    __syncthreads();
    if (tid < 16) {
      double t2 = 0.0;
      for (int g2 = 0; g2 < 16; g2++) t2 += redd[tid * 16 + g2];
      Cm[bid * 16 + tid] = (float)t2;
    }
  }
  __threadfence();
  gg.sync();

  // ---- correction + softmax #2 ----
  {
#pragma unroll
    for (int i = 0; i < 4; i++) {
      int idx4 = tid + i * 256;
      float4 v = *(const float4*)(Cm + idx4 * 4);
      int e0 = idx4 * 4;
      int r = e0 >> 6;
      if ((e0 & 63) == r) v.x = 0.f;
      if (((e0 + 1) & 63) == r) v.y = 0.f;
      if (((e0 + 2) & 63) == r) v.z = 0.f;
      if (((e0 + 3) & 63) == r) v.w = 0.f;
      *(float4*)(Cs + e0) = v;
    }
    __syncthreads();
    float g[16];
#pragma unroll
    for (int j = 0; j < 16; j++) g[j] = 0.f;
    for (int f = 0; f < 64; f++) {
      float mf = ms[tg * 68 + f];
#pragma unroll
      for (int i = 0; i < 4; i++) {
        float4 cv = *(const float4*)(Cs + f * 64 + q * 16 + i * 4);
        g[i * 4 + 0] = fmaf(mf, cv.x, g[i * 4 + 0]);
        g[i * 4 + 1] = fmaf(mf, cv.y, g[i * 4 + 1]);
        g[i * 4 + 2] = fmaf(mf, cv.z, g[i * 4 + 2]);
        g[i * 4 + 3] = fmaf(mf, cv.w, g[i * 4 + 3]);
      }
    }
    float dot = 0.f;
#pragma unroll
    for (int j = 0; j < 16; j++) { g[j] *= 4.f; dot += m[j] * g[j]; }
    dot = warp4_sum(dot);
    float mx = -1e30f;
#pragma unroll
    for (int j = 0; j < 16; j++) {
      l[j] = l[j] - LTAX * (m[j] * (g[j] - dot));
      mx = fmaxf(mx, l[j]);
    }
    mx = warp4_max(mx);
    float ps = 0.f;
#pragma unroll
    for (int j = 0; j < 16; j++) { m[j] = expf(l[j] - mx); ps += m[j]; }
    ps = warp4_sum(ps);
    const float inv = 1.0f / ps;
#pragma unroll
    for (int j = 0; j < 16; j++) m[j] *= inv;
  }

#define STORE_COLSUM(DST) { \
    float cs[16]; \
    _Pragma("unroll") for (int j = 0; j < 16; j++) cs[j] = m[j]; \
    _Pragma("unroll") for (int j = 0; j < 16; j++) { \
      cs[j] += __shfl_xor(cs[j], 4);  cs[j] += __shfl_xor(cs[j], 8); \
      cs[j] += __shfl_xor(cs[j], 16); cs[j] += __shfl_xor(cs[j], 32); } \
    if ((lane >> 2) == 0) { \
      _Pragma("unroll") for (int j = 0; j < 16; j++) cred[w * 64 + lane * 16 + j] = cs[j]; \
    } \
    __syncthreads(); \
    if (tid < 64) (DST)[bid * 64 + tid] = cred[tid] + cred[64 + tid] + cred[128 + tid] + cred[192 + tid]; \
    __syncthreads(); }

  // ---- Sinkhorn: 10 iterations ----
  float* cin = colA;
  float* cot = colB;
  STORE_COLSUM(colA);
  __threadfence();
  gg.sync();
#pragma unroll 1
  for (int it = 0; it < 10; it++) {
    {
      const int e = tid & 63, zq = tid >> 6;
      double s = 0.0;
      for (int z = 0; z < 64; z++) s += (double)cin[(zq * 64 + z) * 64 + e];
      redd[tid] = s;
    }
    __syncthreads();
    if (tid < 64) {
      double s = redd[tid] + redd[64 + tid] + redd[128 + tid] + redd[192 + tid];
      fac[tid] = (float)((1.0 / 256.0) / fmax(s, 1e-12));
    }
    __syncthreads();
    float rs = 0.f;
#pragma unroll
    for (int j = 0; j < 16; j++) { m[j] *= fac[q * 16 + j]; rs += m[j]; }
    rs = warp4_sum(rs);
    const float inv = 1.0f / fmaxf(rs, 1e-12f);
#pragma unroll
    for (int j = 0; j < 16; j++) m[j] *= inv;
    if (it < 9) {
      STORE_COLSUM(cot);
      __threadfence();
      gg.sync();
      float* tt = cin; cin = cot; cot = tt;
    }
  }

  // ---- damping + hysteresis + renorm + top-8 ----
  {
    const int flag = s_flag;
    float pv[16], mk[16];
#pragma unroll
    for (int i = 0; i < 4; i++) {
      float4 v = *(const float4*)(pp + (size_t)row * NE + q * 16 + i * 4);
      pv[i * 4 + 0] = v.x; pv[i * 4 + 1] = v.y; pv[i * 4 + 2] = v.z; pv[i * 4 + 3] = v.w;
    }
    if (flag == 0) {
      const u32* pb = (const u32*)pmask + row * 16 + q * 4;
#pragma unroll
      for (int i = 0; i < 4; i++) {
        u32 ww = pb[i];
        mk[i * 4 + 0] = (ww & 0xffu) ? 1.f : 0.f;
        mk[i * 4 + 1] = (ww & 0xff00u) ? 1.f : 0.f;
        mk[i * 4 + 2] = (ww & 0xff0000u) ? 1.f : 0.f;
        mk[i * 4 + 3] = (ww & 0xff000000u) ? 1.f : 0.f;
      }
    } else if (flag == 1) {
      const int* pb = (const int*)pmask + (size_t)row * NE + q * 16;
#pragma unroll
      for (int j = 0; j < 16; j++) mk[j] = pb[j] ? 1.f : 0.f;
    } else {
      const float* pb = (const float*)pmask + (size_t)row * NE + q * 16;
#pragma unroll
      for (int j = 0; j < 16; j++) mk[j] = (pb[j] != 0.f) ? 1.f : 0.f;
    }
    float msum = 0.f;
#pragma unroll
    for (int j = 0; j < 16; j++) msum += mk[j];
    msum = warp4_sum(msum);
    const float hscale = HYST / fmaxf(msum, 1.0f);
    float v[16];
    float s = 0.f;
#pragma unroll
    for (int j = 0; j < 16; j++) {
      float base = (1.f - ALPHA) * pv[j] + ALPHA * m[j];
      v[j] = (1.f - HYST) * base + hscale * mk[j];
      s += v[j];
    }
    s = warp4_sum(s);
    const float inv = 1.0f / fmaxf(s, 1e-12f);
#pragma unroll
    for (int j = 0; j < 16; j++) v[j] *= inv;

    float* mout = out;
    float* kout = out + (size_t)NT * NE;
#pragma unroll
    for (int i = 0; i < 4; i++)
      *(float4*)(mout + (size_t)row * NE + q * 16 + i * 4) =
          make_float4(v[i * 4], v[i * 4 + 1], v[i * 4 + 2], v[i * 4 + 3]);

    int cnt[16];
#pragma unroll
    for (int j = 0; j < 16; j++) cnt[j] = 0;
    const int base = lane & ~3;
#pragma unroll
    for (int oq = 0; oq < 4; oq++) {
#pragma unroll
      for (int j2 = 0; j2 < 16; j2++) {
        float ov = __shfl(v[j2], base + oq, 64);
        int oe = oq * 16 + j2;
#pragma unroll
        for (int j = 0; j < 16; j++) {
          int me = q * 16 + j;
          if (ov > v[j] || (ov == v[j] && oe < me)) cnt[j]++;
        }
      }
    }
#pragma unroll
    for (int i = 0; i < 4; i++)
      *(float4*)(kout + (size_t)row * NE + q * 16 + i * 4) =
          make_float4(cnt[i * 4] < TOPK ? 1.f : 0.f, cnt[i * 4 + 1] < TOPK ? 1.f : 0.f,
                      cnt[i * 4 + 2] < TOPK ? 1.f : 0.f, cnt[i * 4 + 3] < TOPK ? 1.f : 0.f);
  }
}

extern "C" void kernel_launch(void* const* d_in, const int* in_sizes, int n_in,
                              void* d_out, int out_size, void* d_ws, size_t ws_size,
                              hipStream_t stream) {
  const float* x = (const float*)d_in[0];
  const float* W = (const float*)d_in[1];
  const float* b = (const float*)d_in[2];
  const float* pp = (const float*)d_in[3];
  const void* pmask = d_in[4];
  float* out = (float*)d_out;

  unsigned char* wsb = (unsigned char*)d_ws;
  u16* Wh = (u16*)(wsb);                          // 256 KB
  u16* Wm = (u16*)(wsb + 262144);                 // 256 KB
  u16* Wl = (u16*)(wsb + 524288);                 // 256 KB
  double* Lpart = (double*)(wsb + 786432);        // 2 * NT*NE * 8 = 16 MB
  float* Cpart = (float*)(wsb + 17563648);        // 4 MB
  float* Cm = (float*)(wsb + 21757952);           // 16 KB
  float* colA = (float*)(wsb + 21774336);         // 64 KB
  float* colB = (float*)(wsb + 21839872);         // 64 KB

  k_wsplit3<<<128, 256, 0, stream>>>(W, Wh, Wm, Wl);
  k_gemm<<<512, 256, 0, stream>>>(x, Wh, Wm, Wl, Lpart);

  void* args[] = {(void*)&Lpart, (void*)&b, (void*)&pp, (void*)&pmask,
                  (void*)&Cpart, (void*)&Cm, (void*)&colA, (void*)&colB, (void*)&out};
  hipLaunchCooperativeKernel((void*)k_router, dim3(256), dim3(256), args, 0, stream);
}

// Round 8
// 315.920 us; speedup vs baseline: 2.6845x; 2.6845x over previous
//
#include <hip/hip_runtime.h>
#include <hip/hip_cooperative_groups.h>
#include <math.h>

#define NT 16384
#define DM 2048
#define NE 64
#define TOPK 8
#define LTAX 0.04f
#define HYST 0.1f
#define ALPHA 0.7f

typedef unsigned int u32;
typedef unsigned short u16;
typedef unsigned long long u64;
typedef __attribute__((ext_vector_type(8))) short bf16x8;
typedef __attribute__((ext_vector_type(4))) float f32x4;

__device__ __forceinline__ float warp4_sum(float v) {
  v += __shfl_xor(v, 1); v += __shfl_xor(v, 2); return v;
}
__device__ __forceinline__ float warp4_max(float v) {
  v = fmaxf(v, __shfl_xor(v, 1)); v = fmaxf(v, __shfl_xor(v, 2)); return v;
}
__device__ __forceinline__ u16 f2bf(float f) {   // RNE f32->bf16
  u32 u = __float_as_uint(f);
  return (u16)((u + 0x7fffu + ((u >> 16) & 1u)) >> 16);
}
__device__ __forceinline__ float bf2f(u16 h) { return __uint_as_float(((u32)h) << 16); }

__device__ __forceinline__ void split3(float a, short& h, short& m, short& l) {
  u16 hh = f2bf(a);  float r1 = a - bf2f(hh);     // exact (Sterbenz)
  u16 mm = f2bf(r1); float r2 = r1 - bf2f(mm);    // exact
  h = (short)hh; m = (short)mm; l = (short)f2bf(r2);
}

// fixed-point 2^32 helpers: exact-commutative integer atomics => deterministic
__device__ __forceinline__ u64 to_fx(float v) {
  return (u64)__double2ll_rn((double)v * 4294967296.0);
}
__device__ __forceinline__ float from_fx(u64 u) {
  return (float)((double)u * (1.0 / 4294967296.0));
}
__device__ __forceinline__ u64 aload_u64(const u64* p) {
  return __hip_atomic_load(p, __ATOMIC_RELAXED, __HIP_MEMORY_SCOPE_AGENT);
}
// arrive + spin barrier; release makes this block's prior atomics visible,
// acquire makes other blocks' released data visible. No bulk L2 flush.
__device__ __forceinline__ void gbar(u32* ctr, u32 target) {
  __syncthreads();
  if (threadIdx.x == 0) {
    __hip_atomic_fetch_add(ctr, 1u, __ATOMIC_RELEASE, __HIP_MEMORY_SCOPE_AGENT);
    u32 v;
    do {
      __builtin_amdgcn_s_sleep(8);
      v = __hip_atomic_load(ctr, __ATOMIC_ACQUIRE, __HIP_MEMORY_SCOPE_AGENT);
    } while (v < target);
  }
  __syncthreads();
}

// ---------------- K0: W -> bf16 hi/mid/lo ----------------------------------
__global__ void k_wsplit3(const float* __restrict__ W, u16* __restrict__ Wh,
                          u16* __restrict__ Wm, u16* __restrict__ Wl) {
  int idx = (blockIdx.x * 256 + threadIdx.x) * 4;
  float4 v = *(const float4*)(W + idx);
  short h[4], m[4], l[4];
  split3(v.x, h[0], m[0], l[0]);
  split3(v.y, h[1], m[1], l[1]);
  split3(v.z, h[2], m[2], l[2]);
  split3(v.w, h[3], m[3], l[3]);
  *(ushort4*)(Wh + idx) = make_ushort4((u16)h[0], (u16)h[1], (u16)h[2], (u16)h[3]);
  *(ushort4*)(Wm + idx) = make_ushort4((u16)m[0], (u16)m[1], (u16)m[2], (u16)m[3]);
  *(ushort4*)(Wl + idx) = make_ushort4((u16)l[0], (u16)l[1], (u16)l[2], (u16)l[3]);
}

// ---------------- K1: MFMA GEMM, split-K=2, f64 partials (unchanged R7) -----
__launch_bounds__(256, 2)
__global__ void k_gemm(const float* __restrict__ x, const u16* __restrict__ Whg,
                       const u16* __restrict__ Wmg, const u16* __restrict__ Wlg,
                       double* __restrict__ Lpart) {
  __shared__ __align__(16) u16 XS[30720];   // 6 arrays x 2 buf x [64][40]
  const int tid = threadIdx.x;
  const int bid = blockIdx.x;
  const int tile = bid >> 1, ks = bid & 1;
  const int row0 = tile * 64;
  const int k0 = ks * 1024;
  const int lane = tid & 63, w = tid >> 6, l15 = lane & 15, l4 = lane >> 4;
  const int srow = tid >> 2, c8 = (tid & 3) * 8;
  const int stoff = srow * 40 + c8;

  f32x4 accA[4], accB[4];
  double accD[4][4];
#pragma unroll
  for (int eb = 0; eb < 4; eb++) {
    accA[eb] = (f32x4)0.f; accB[eb] = (f32x4)0.f;
#pragma unroll
    for (int r = 0; r < 4; r++) accD[eb][r] = 0.0;
  }

  float4 xq0, xq1;
  uint4 whv, wmv, wlv;
  const float* xrowp = x + (size_t)(row0 + srow) * DM + k0 + c8;
  const u16* whp = Whg + srow * DM + k0 + c8;
  const u16* wmp = Wmg + srow * DM + k0 + c8;
  const u16* wlp = Wlg + srow * DM + k0 + c8;

#define LOADCH(KC) { \
    xq0 = *(const float4*)(xrowp + (KC)); \
    xq1 = *(const float4*)(xrowp + (KC) + 4); \
    whv = *(const uint4*)(whp + (KC)); \
    wmv = *(const uint4*)(wmp + (KC)); \
    wlv = *(const uint4*)(wlp + (KC)); }

#define WRITECH(B) { \
    short ha[8], ma[8], la[8]; \
    split3(xq0.x, ha[0], ma[0], la[0]); \
    split3(xq0.y, ha[1], ma[1], la[1]); \
    split3(xq0.z, ha[2], ma[2], la[2]); \
    split3(xq0.w, ha[3], ma[3], la[3]); \
    split3(xq1.x, ha[4], ma[4], la[4]); \
    split3(xq1.y, ha[5], ma[5], la[5]); \
    split3(xq1.z, ha[6], ma[6], la[6]); \
    split3(xq1.w, ha[7], ma[7], la[7]); \
    bf16x8 xh8, xm8, xl8; \
    _Pragma("unroll") \
    for (int z = 0; z < 8; z++) { xh8[z] = ha[z]; xm8[z] = ma[z]; xl8[z] = la[z]; } \
    *(bf16x8*)(XS + 0     + (B) * 2560 + stoff) = xh8; \
    *(bf16x8*)(XS + 5120  + (B) * 2560 + stoff) = xm8; \
    *(bf16x8*)(XS + 10240 + (B) * 2560 + stoff) = xl8; \
    *(uint4*)(XS + 15360 + (B) * 2560 + stoff) = whv; \
    *(uint4*)(XS + 20480 + (B) * 2560 + stoff) = wmv; \
    *(uint4*)(XS + 25600 + (B) * 2560 + stoff) = wlv; }

#define COMPUTECH(B) { \
    const int ar = (w * 16 + l15) * 40 + l4 * 8; \
    bf16x8 ah = *(const bf16x8*)(XS + 0     + (B) * 2560 + ar); \
    bf16x8 am = *(const bf16x8*)(XS + 5120  + (B) * 2560 + ar); \
    bf16x8 al = *(const bf16x8*)(XS + 10240 + (B) * 2560 + ar); \
    _Pragma("unroll") \
    for (int eb = 0; eb < 4; eb++) { \
      const int br = (eb * 16 + l15) * 40 + l4 * 8; \
      bf16x8 bh = *(const bf16x8*)(XS + 15360 + (B) * 2560 + br); \
      bf16x8 bm = *(const bf16x8*)(XS + 20480 + (B) * 2560 + br); \
      bf16x8 bl = *(const bf16x8*)(XS + 25600 + (B) * 2560 + br); \
      accA[eb] = __builtin_amdgcn_mfma_f32_16x16x32_bf16(ah, bh, accA[eb], 0, 0, 0); \
      accB[eb] = __builtin_amdgcn_mfma_f32_16x16x32_bf16(ah, bm, accB[eb], 0, 0, 0); \
      accB[eb] = __builtin_amdgcn_mfma_f32_16x16x32_bf16(am, bh, accB[eb], 0, 0, 0); \
      accB[eb] = __builtin_amdgcn_mfma_f32_16x16x32_bf16(am, bm, accB[eb], 0, 0, 0); \
      accB[eb] = __builtin_amdgcn_mfma_f32_16x16x32_bf16(ah, bl, accB[eb], 0, 0, 0); \
      accB[eb] = __builtin_amdgcn_mfma_f32_16x16x32_bf16(al, bh, accB[eb], 0, 0, 0); \
    } }

  LOADCH(0);
  WRITECH(0);
  __syncthreads();
#pragma unroll 1
  for (int t = 0; t < 32; t++) {
    if (t < 31) LOADCH((t + 1) * 32);
    COMPUTECH(t & 1);
    if ((t & 7) == 7) {               // drain f32 accs into f64 (K=256 slices)
#pragma unroll
      for (int eb = 0; eb < 4; eb++) {
#pragma unroll
        for (int r = 0; r < 4; r++)
          accD[eb][r] += (double)accA[eb][r] + (double)accB[eb][r];
        accA[eb] = (f32x4)0.f; accB[eb] = (f32x4)0.f;
      }
    }
    if (t < 31) WRITECH((t + 1) & 1);
    __syncthreads();
  }

  double* outp = Lpart + (size_t)ks * NT * NE;
#pragma unroll
  for (int eb = 0; eb < 4; eb++)
#pragma unroll
    for (int r = 0; r < 4; r++) {
      int trow = w * 16 + l4 * 4 + r;
      outp[(size_t)(row0 + trow) * NE + eb * 16 + l15] = accD[eb][r];
    }
}

// ---------------- K2: cooperative tail with atomic barriers -----------------
__launch_bounds__(256, 1)
__global__ void k_tail(const double* __restrict__ Lpart, const float* __restrict__ b,
                       const float* __restrict__ pp, const void* __restrict__ pmask,
                       u64* __restrict__ CmAcc, u64* __restrict__ colAcc,
                       u32* __restrict__ ctr, float* __restrict__ out) {
  __shared__ __align__(16) float ms[64 * 68];
  __shared__ __align__(16) float Cs[4096];
  __shared__ float cred[4 * 64];
  __shared__ float fac[64];
  __shared__ int s_cnt[256];
  __shared__ int s_flag;

  const int tid = threadIdx.x;
  const int bid = blockIdx.x;
  const int lane = tid & 63;
  const int w = tid >> 6;
  const int row0 = bid * 64;

  // ---- prev_mask format detect (first 4096 bytes; deterministic) ----
  {
    uint4 v = ((const uint4*)pmask)[tid];
    int c = 0; u32 ww;
    ww = v.x; c += ((ww & 0xffu) != 0) + ((ww & 0xff00u) != 0) + ((ww & 0xff0000u) != 0) + ((ww & 0xff000000u) != 0);
    ww = v.y; c += ((ww & 0xffu) != 0) + ((ww & 0xff00u) != 0) + ((ww & 0xff0000u) != 0) + ((ww & 0xff000000u) != 0);
    ww = v.z; c += ((ww & 0xffu) != 0) + ((ww & 0xff00u) != 0) + ((ww & 0xff0000u) != 0) + ((ww & 0xff000000u) != 0);
    ww = v.w; c += ((ww & 0xffu) != 0) + ((ww & 0xff00u) != 0) + ((ww & 0xff0000u) != 0) + ((ww & 0xff000000u) != 0);
    s_cnt[tid] = c;
    __syncthreads();
    for (int s = 128; s; s >>= 1) { if (tid < s) s_cnt[tid] += s_cnt[tid + s]; __syncthreads(); }
    if (tid == 0) { int n = s_cnt[0]; s_flag = (n > 384) ? 0 : ((n > 192) ? 2 : 1); }
    __syncthreads();
  }

  // ---- logits from f64 partials + bias; center; softmax #1 ----
  const int tg = tid >> 2, q = tid & 3;
  const int row = row0 + tg;
  float l[16], m[16];
  {
    const double* p0 = Lpart + (size_t)row * NE + q * 16;
    const double* p1 = p0 + (size_t)NT * NE;
#pragma unroll
    for (int i = 0; i < 4; i++) {
      float4 bv = *(const float4*)(b + q * 16 + i * 4);
      l[i * 4 + 0] = (float)(p0[i * 4 + 0] + p1[i * 4 + 0]) + bv.x;
      l[i * 4 + 1] = (float)(p0[i * 4 + 1] + p1[i * 4 + 1]) + bv.y;
      l[i * 4 + 2] = (float)(p0[i * 4 + 2] + p1[i * 4 + 2]) + bv.z;
      l[i * 4 + 3] = (float)(p0[i * 4 + 3] + p1[i * 4 + 3]) + bv.w;
    }
    float s = 0.f;
#pragma unroll
    for (int j = 0; j < 16; j++) s += l[j];
    s = warp4_sum(s);
    const float mean = s * (1.0f / 64.0f);
    float mx = -1e30f;
#pragma unroll
    for (int j = 0; j < 16; j++) { l[j] -= mean; mx = fmaxf(mx, l[j]); }
    mx = warp4_max(mx);
    float ps = 0.f;
#pragma unroll
    for (int j = 0; j < 16; j++) { m[j] = expf(l[j] - mx); ps += m[j]; }
    ps = warp4_sum(ps);
    const float inv = 1.0f / ps;
#pragma unroll
    for (int j = 0; j < 16; j++) m[j] *= inv;
#pragma unroll
    for (int i = 0; i < 4; i++)
      *(float4*)(ms + tg * 68 + q * 16 + i * 4) =
          make_float4(m[i * 4], m[i * 4 + 1], m[i * 4 + 2], m[i * 4 + 3]);
  }
  __syncthreads();

  // ---- gram partial -> fixed-point atomic accumulate ----
  {
    const int gi0 = (tid >> 4) * 4;
    const int gj0 = (tid & 15) * 4;
    float ga[4][4];
#pragma unroll
    for (int a = 0; a < 4; a++)
#pragma unroll
      for (int c = 0; c < 4; c++) ga[a][c] = 0.f;
    for (int t = 0; t < 64; t++) {
      float4 a = *(const float4*)(ms + t * 68 + gi0);
      float4 bb = *(const float4*)(ms + t * 68 + gj0);
      ga[0][0] = fmaf(a.x, bb.x, ga[0][0]); ga[0][1] = fmaf(a.x, bb.y, ga[0][1]);
      ga[0][2] = fmaf(a.x, bb.z, ga[0][2]); ga[0][3] = fmaf(a.x, bb.w, ga[0][3]);
      ga[1][0] = fmaf(a.y, bb.x, ga[1][0]); ga[1][1] = fmaf(a.y, bb.y, ga[1][1]);
      ga[1][2] = fmaf(a.y, bb.z, ga[1][2]); ga[1][3] = fmaf(a.y, bb.w, ga[1][3]);
      ga[2][0] = fmaf(a.z, bb.x, ga[2][0]); ga[2][1] = fmaf(a.z, bb.y, ga[2][1]);
      ga[2][2] = fmaf(a.z, bb.z, ga[2][2]); ga[2][3] = fmaf(a.z, bb.w, ga[2][3]);
      ga[3][0] = fmaf(a.w, bb.x, ga[3][0]); ga[3][1] = fmaf(a.w, bb.y, ga[3][1]);
      ga[3][2] = fmaf(a.w, bb.z, ga[3][2]); ga[3][3] = fmaf(a.w, bb.w, ga[3][3]);
    }
#pragma unroll
    for (int ii = 0; ii < 4; ii++)
#pragma unroll
      for (int jj = 0; jj < 4; jj++)
        atomicAdd(CmAcc + (gi0 + ii) * 64 + gj0 + jj, to_fx(ga[ii][jj]));
  }
  gbar(ctr + 0, 256);

  // ---- load C (coherent), zero diag ----
  {
#pragma unroll 4
    for (int i = 0; i < 16; i++) {
      int idx = tid + i * 256;
      float v = from_fx(aload_u64(CmAcc + idx));
      int r = idx >> 6, c = idx & 63;
      Cs[idx] = (r == c) ? 0.f : v;
    }
  }
  __syncthreads();

  // ---- correction + softmax #2 ----
  {
    float g[16];
#pragma unroll
    for (int j = 0; j < 16; j++) g[j] = 0.f;
    for (int f = 0; f < 64; f++) {
      float mf = ms[tg * 68 + f];
#pragma unroll
      for (int i = 0; i < 4; i++) {
        float4 cv = *(const float4*)(Cs + f * 64 + q * 16 + i * 4);
        g[i * 4 + 0] = fmaf(mf, cv.x, g[i * 4 + 0]);
        g[i * 4 + 1] = fmaf(mf, cv.y, g[i * 4 + 1]);
        g[i * 4 + 2] = fmaf(mf, cv.z, g[i * 4 + 2]);
        g[i * 4 + 3] = fmaf(mf, cv.w, g[i * 4 + 3]);
      }
    }
    float dot = 0.f;
#pragma unroll
    for (int j = 0; j < 16; j++) { g[j] *= 4.f; dot += m[j] * g[j]; }
    dot = warp4_sum(dot);
    float mx = -1e30f;
#pragma unroll
    for (int j = 0; j < 16; j++) {
      l[j] = l[j] - LTAX * (m[j] * (g[j] - dot));
      mx = fmaxf(mx, l[j]);
    }
    mx = warp4_max(mx);
    float ps = 0.f;
#pragma unroll
    for (int j = 0; j < 16; j++) { m[j] = expf(l[j] - mx); ps += m[j]; }
    ps = warp4_sum(ps);
    const float inv = 1.0f / ps;
#pragma unroll
    for (int j = 0; j < 16; j++) m[j] *= inv;
  }

#define COLSUM_ADD(K) { \
    float cs[16]; \
    _Pragma("unroll") for (int j = 0; j < 16; j++) cs[j] = m[j]; \
    _Pragma("unroll") for (int j = 0; j < 16; j++) { \
      cs[j] += __shfl_xor(cs[j], 4);  cs[j] += __shfl_xor(cs[j], 8); \
      cs[j] += __shfl_xor(cs[j], 16); cs[j] += __shfl_xor(cs[j], 32); } \
    if ((lane >> 2) == 0) { \
      _Pragma("unroll") for (int j = 0; j < 16; j++) cred[w * 64 + lane * 16 + j] = cs[j]; \
    } \
    __syncthreads(); \
    if (tid < 64) \
      atomicAdd(colAcc + (K) * 64 + tid, \
                to_fx(cred[tid] + cred[64 + tid] + cred[128 + tid] + cred[192 + tid])); }

  // ---- Sinkhorn: 10 iterations, atomic col-sum exchange ----
  COLSUM_ADD(0);
  gbar(ctr + 1, 256);
#pragma unroll 1
  for (int it = 0; it < 10; it++) {
    if (tid < 64) {
      double s = (double)aload_u64(colAcc + it * 64 + tid) * (1.0 / 4294967296.0);
      fac[tid] = (float)((1.0 / 256.0) / fmax(s, 1e-12));
    }
    __syncthreads();
    float rs = 0.f;
#pragma unroll
    for (int j = 0; j < 16; j++) { m[j] *= fac[q * 16 + j]; rs += m[j]; }
    rs = warp4_sum(rs);
    const float inv = 1.0f / fmaxf(rs, 1e-12f);
#pragma unroll
    for (int j = 0; j < 16; j++) m[j] *= inv;
    if (it < 9) {
      COLSUM_ADD(it + 1);
      gbar(ctr + 2 + it, 256);
    }
  }

  // ---- damping + hysteresis + renorm + top-8 ----
  {
    const int flag = s_flag;
    float pv[16], mk[16];
#pragma unroll
    for (int i = 0; i < 4; i++) {
      float4 v = *(const float4*)(pp + (size_t)row * NE + q * 16 + i * 4);
      pv[i * 4 + 0] = v.x; pv[i * 4 + 1] = v.y; pv[i * 4 + 2] = v.z; pv[i * 4 + 3] = v.w;
    }
    if (flag == 0) {
      const u32* pb = (const u32*)pmask + row * 16 + q * 4;
#pragma unroll
      for (int i = 0; i < 4; i++) {
        u32 ww = pb[i];
        mk[i * 4 + 0] = (ww & 0xffu) ? 1.f : 0.f;
        mk[i * 4 + 1] = (ww & 0xff00u) ? 1.f : 0.f;
        mk[i * 4 + 2] = (ww & 0xff0000u) ? 1.f : 0.f;
        mk[i * 4 + 3] = (ww & 0xff000000u) ? 1.f : 0.f;
      }
    } else if (flag == 1) {
      const int* pb = (const int*)pmask + (size_t)row * NE + q * 16;
#pragma unroll
      for (int j = 0; j < 16; j++) mk[j] = pb[j] ? 1.f : 0.f;
    } else {
      const float* pb = (const float*)pmask + (size_t)row * NE + q * 16;
#pragma unroll
      for (int j = 0; j < 16; j++) mk[j] = (pb[j] != 0.f) ? 1.f : 0.f;
    }
    float msum = 0.f;
#pragma unroll
    for (int j = 0; j < 16; j++) msum += mk[j];
    msum = warp4_sum(msum);
    const float hscale = HYST / fmaxf(msum, 1.0f);
    float v[16];
    float s = 0.f;
#pragma unroll
    for (int j = 0; j < 16; j++) {
      float base = (1.f - ALPHA) * pv[j] + ALPHA * m[j];
      v[j] = (1.f - HYST) * base + hscale * mk[j];
      s += v[j];
    }
    s = warp4_sum(s);
    const float inv = 1.0f / fmaxf(s, 1e-12f);
#pragma unroll
    for (int j = 0; j < 16; j++) v[j] *= inv;

    float* mout = out;
    float* kout = out + (size_t)NT * NE;
#pragma unroll
    for (int i = 0; i < 4; i++)
      *(float4*)(mout + (size_t)row * NE + q * 16 + i * 4) =
          make_float4(v[i * 4], v[i * 4 + 1], v[i * 4 + 2], v[i * 4 + 3]);

    int cnt[16];
#pragma unroll
    for (int j = 0; j < 16; j++) cnt[j] = 0;
    const int base = lane & ~3;
#pragma unroll
    for (int oq = 0; oq < 4; oq++) {
#pragma unroll
      for (int j2 = 0; j2 < 16; j2++) {
        float ov = __shfl(v[j2], base + oq, 64);
        int oe = oq * 16 + j2;
#pragma unroll
        for (int j = 0; j < 16; j++) {
          int me = q * 16 + j;
          if (ov > v[j] || (ov == v[j] && oe < me)) cnt[j]++;
        }
      }
    }
#pragma unroll
    for (int i = 0; i < 4; i++)
      *(float4*)(kout + (size_t)row * NE + q * 16 + i * 4) =
          make_float4(cnt[i * 4] < TOPK ? 1.f : 0.f, cnt[i * 4 + 1] < TOPK ? 1.f : 0.f,
                      cnt[i * 4 + 2] < TOPK ? 1.f : 0.f, cnt[i * 4 + 3] < TOPK ? 1.f : 0.f);
  }
}

extern "C" void kernel_launch(void* const* d_in, const int* in_sizes, int n_in,
                              void* d_out, int out_size, void* d_ws, size_t ws_size,
                              hipStream_t stream) {
  const float* x = (const float*)d_in[0];
  const float* W = (const float*)d_in[1];
  const float* b = (const float*)d_in[2];
  const float* pp = (const float*)d_in[3];
  const void* pmask = d_in[4];
  float* out = (float*)d_out;

  unsigned char* wsb = (unsigned char*)d_ws;
  u16* Wh = (u16*)(wsb);                          // 256 KB
  u16* Wm = (u16*)(wsb + 262144);                 // 256 KB
  u16* Wl = (u16*)(wsb + 524288);                 // 256 KB
  double* Lpart = (double*)(wsb + 786432);        // 16 MB
  u64* CmAcc = (u64*)(wsb + 17563648);            // 4096 u64 = 32 KB
  u64* colAcc = (u64*)(wsb + 17596416);           // 10*64 u64 = 5 KB
  u32* ctr = (u32*)(wsb + 17601536);              // 16 u32

  // zero the atomic accumulators + barrier counters (graph-capture safe)
  hipMemsetAsync(wsb + 17563648, 0, 37952, stream);
  k_wsplit3<<<128, 256, 0, stream>>>(W, Wh, Wm, Wl);
  k_gemm<<<512, 256, 0, stream>>>(x, Wh, Wm, Wl, Lpart);

  void* args[] = {(void*)&Lpart, (void*)&b, (void*)&pp, (void*)&pmask,
                  (void*)&CmAcc, (void*)&colAcc, (void*)&ctr, (void*)&out};
  hipLaunchCooperativeKernel((void*)k_tail, dim3(256), dim3(256), args, 0, stream);
}

// Round 9
// 301.466 us; speedup vs baseline: 2.8132x; 1.0479x over previous
//
#include <hip/hip_runtime.h>
#include <hip/hip_cooperative_groups.h>
#include <math.h>

#define NT 16384
#define DM 2048
#define NE 64
#define TOPK 8
#define LTAX 0.04f
#define HYST 0.1f
#define ALPHA 0.7f

typedef unsigned int u32;
typedef unsigned short u16;
typedef unsigned long long u64;
typedef __attribute__((ext_vector_type(8))) short bf16x8;
typedef __attribute__((ext_vector_type(4))) float f32x4;

__device__ __forceinline__ float warp4_sum(float v) {
  v += __shfl_xor(v, 1); v += __shfl_xor(v, 2); return v;
}
__device__ __forceinline__ float warp4_max(float v) {
  v = fmaxf(v, __shfl_xor(v, 1)); v = fmaxf(v, __shfl_xor(v, 2)); return v;
}
__device__ __forceinline__ u16 f2bf(float f) {   // RNE f32->bf16
  u32 u = __float_as_uint(f);
  return (u16)((u + 0x7fffu + ((u >> 16) & 1u)) >> 16);
}
__device__ __forceinline__ float bf2f(u16 h) { return __uint_as_float(((u32)h) << 16); }

__device__ __forceinline__ void split3(float a, short& h, short& m, short& l) {
  u16 hh = f2bf(a);  float r1 = a - bf2f(hh);     // exact (Sterbenz)
  u16 mm = f2bf(r1); float r2 = r1 - bf2f(mm);    // exact
  h = (short)hh; m = (short)mm; l = (short)f2bf(r2);
}

// fixed-point 2^32 helpers: exact-commutative integer atomics => deterministic
__device__ __forceinline__ u64 to_fx(float v) {
  return (u64)__double2ll_rn((double)v * 4294967296.0);
}
__device__ __forceinline__ float from_fx(u64 u) {
  return (float)((double)u * (1.0 / 4294967296.0));
}
__device__ __forceinline__ u64 aload_u64(const u64* p) {
  return __hip_atomic_load(p, __ATOMIC_RELAXED, __HIP_MEMORY_SCOPE_AGENT);
}
__device__ __forceinline__ void gbar(u32* ctr, u32 target) {
  __syncthreads();
  if (threadIdx.x == 0) {
    __hip_atomic_fetch_add(ctr, 1u, __ATOMIC_RELEASE, __HIP_MEMORY_SCOPE_AGENT);
    u32 v;
    do {
      __builtin_amdgcn_s_sleep(8);
      v = __hip_atomic_load(ctr, __ATOMIC_ACQUIRE, __HIP_MEMORY_SCOPE_AGENT);
    } while (v < target);
  }
  __syncthreads();
}

// ---------------- K0: W -> bf16 hi/mid/lo ----------------------------------
__global__ void k_wsplit3(const float* __restrict__ W, u16* __restrict__ Wh,
                          u16* __restrict__ Wm, u16* __restrict__ Wl) {
  int idx = (blockIdx.x * 256 + threadIdx.x) * 4;
  float4 v = *(const float4*)(W + idx);
  short h[4], m[4], l[4];
  split3(v.x, h[0], m[0], l[0]);
  split3(v.y, h[1], m[1], l[1]);
  split3(v.z, h[2], m[2], l[2]);
  split3(v.w, h[3], m[3], l[3]);
  *(ushort4*)(Wh + idx) = make_ushort4((u16)h[0], (u16)h[1], (u16)h[2], (u16)h[3]);
  *(ushort4*)(Wm + idx) = make_ushort4((u16)m[0], (u16)m[1], (u16)m[2], (u16)m[3]);
  *(ushort4*)(Wl + idx) = make_ushort4((u16)l[0], (u16)l[1], (u16)l[2], (u16)l[3]);
}

// ---------------- K1: MFMA GEMM, split-K=2, f64 partials (unchanged) --------
__launch_bounds__(256, 2)
__global__ void k_gemm(const float* __restrict__ x, const u16* __restrict__ Whg,
                       const u16* __restrict__ Wmg, const u16* __restrict__ Wlg,
                       double* __restrict__ Lpart) {
  __shared__ __align__(16) u16 XS[30720];   // 6 arrays x 2 buf x [64][40]
  const int tid = threadIdx.x;
  const int bid = blockIdx.x;
  const int tile = bid >> 1, ks = bid & 1;
  const int row0 = tile * 64;
  const int k0 = ks * 1024;
  const int lane = tid & 63, w = tid >> 6, l15 = lane & 15, l4 = lane >> 4;
  const int srow = tid >> 2, c8 = (tid & 3) * 8;
  const int stoff = srow * 40 + c8;

  f32x4 accA[4], accB[4];
  double accD[4][4];
#pragma unroll
  for (int eb = 0; eb < 4; eb++) {
    accA[eb] = (f32x4)0.f; accB[eb] = (f32x4)0.f;
#pragma unroll
    for (int r = 0; r < 4; r++) accD[eb][r] = 0.0;
  }

  float4 xq0, xq1;
  uint4 whv, wmv, wlv;
  const float* xrowp = x + (size_t)(row0 + srow) * DM + k0 + c8;
  const u16* whp = Whg + srow * DM + k0 + c8;
  const u16* wmp = Wmg + srow * DM + k0 + c8;
  const u16* wlp = Wlg + srow * DM + k0 + c8;

#define LOADCH(KC) { \
    xq0 = *(const float4*)(xrowp + (KC)); \
    xq1 = *(const float4*)(xrowp + (KC) + 4); \
    whv = *(const uint4*)(whp + (KC)); \
    wmv = *(const uint4*)(wmp + (KC)); \
    wlv = *(const uint4*)(wlp + (KC)); }

#define WRITECH(B) { \
    short ha[8], ma[8], la[8]; \
    split3(xq0.x, ha[0], ma[0], la[0]); \
    split3(xq0.y, ha[1], ma[1], la[1]); \
    split3(xq0.z, ha[2], ma[2], la[2]); \
    split3(xq0.w, ha[3], ma[3], la[3]); \
    split3(xq1.x, ha[4], ma[4], la[4]); \
    split3(xq1.y, ha[5], ma[5], la[5]); \
    split3(xq1.z, ha[6], ma[6], la[6]); \
    split3(xq1.w, ha[7], ma[7], la[7]); \
    bf16x8 xh8, xm8, xl8; \
    _Pragma("unroll") \
    for (int z = 0; z < 8; z++) { xh8[z] = ha[z]; xm8[z] = ma[z]; xl8[z] = la[z]; } \
    *(bf16x8*)(XS + 0     + (B) * 2560 + stoff) = xh8; \
    *(bf16x8*)(XS + 5120  + (B) * 2560 + stoff) = xm8; \
    *(bf16x8*)(XS + 10240 + (B) * 2560 + stoff) = xl8; \
    *(uint4*)(XS + 15360 + (B) * 2560 + stoff) = whv; \
    *(uint4*)(XS + 20480 + (B) * 2560 + stoff) = wmv; \
    *(uint4*)(XS + 25600 + (B) * 2560 + stoff) = wlv; }

#define COMPUTECH(B) { \
    const int ar = (w * 16 + l15) * 40 + l4 * 8; \
    bf16x8 ah = *(const bf16x8*)(XS + 0     + (B) * 2560 + ar); \
    bf16x8 am = *(const bf16x8*)(XS + 5120  + (B) * 2560 + ar); \
    bf16x8 al = *(const bf16x8*)(XS + 10240 + (B) * 2560 + ar); \
    _Pragma("unroll") \
    for (int eb = 0; eb < 4; eb++) { \
      const int br = (eb * 16 + l15) * 40 + l4 * 8; \
      bf16x8 bh = *(const bf16x8*)(XS + 15360 + (B) * 2560 + br); \
      bf16x8 bm = *(const bf16x8*)(XS + 20480 + (B) * 2560 + br); \
      bf16x8 bl = *(const bf16x8*)(XS + 25600 + (B) * 2560 + br); \
      accA[eb] = __builtin_amdgcn_mfma_f32_16x16x32_bf16(ah, bh, accA[eb], 0, 0, 0); \
      accB[eb] = __builtin_amdgcn_mfma_f32_16x16x32_bf16(ah, bm, accB[eb], 0, 0, 0); \
      accB[eb] = __builtin_amdgcn_mfma_f32_16x16x32_bf16(am, bh, accB[eb], 0, 0, 0); \
      accB[eb] = __builtin_amdgcn_mfma_f32_16x16x32_bf16(am, bm, accB[eb], 0, 0, 0); \
      accB[eb] = __builtin_amdgcn_mfma_f32_16x16x32_bf16(ah, bl, accB[eb], 0, 0, 0); \
      accB[eb] = __builtin_amdgcn_mfma_f32_16x16x32_bf16(al, bh, accB[eb], 0, 0, 0); \
    } }

  LOADCH(0);
  WRITECH(0);
  __syncthreads();
#pragma unroll 1
  for (int t = 0; t < 32; t++) {
    if (t < 31) LOADCH((t + 1) * 32);
    COMPUTECH(t & 1);
    if ((t & 7) == 7) {
#pragma unroll
      for (int eb = 0; eb < 4; eb++) {
#pragma unroll
        for (int r = 0; r < 4; r++)
          accD[eb][r] += (double)accA[eb][r] + (double)accB[eb][r];
        accA[eb] = (f32x4)0.f; accB[eb] = (f32x4)0.f;
      }
    }
    if (t < 31) WRITECH((t + 1) & 1);
    __syncthreads();
  }

  double* outp = Lpart + (size_t)ks * NT * NE;
#pragma unroll
  for (int eb = 0; eb < 4; eb++)
#pragma unroll
    for (int r = 0; r < 4; r++) {
      int trow = w * 16 + l4 * 4 + r;
      outp[(size_t)(row0 + trow) * NE + eb * 16 + l15] = accD[eb][r];
    }
}

// ---------------- K2: cooperative tail, 64 blocks x 256 tokens --------------
// 4 sequential 64-token groups/block. M + logits live in registers
// (m[4][16], l[4][16]); ms LDS buffer reused per group for gram/correction.
#define NB 64
__launch_bounds__(256, 1)
__global__ void k_tail(const double* __restrict__ Lpart, const float* __restrict__ b,
                       const float* __restrict__ pp, const void* __restrict__ pmask,
                       u64* __restrict__ CmAcc, u64* __restrict__ colAcc,
                       u32* __restrict__ ctr, float* __restrict__ out) {
  __shared__ __align__(16) float ms[64 * 68];
  __shared__ __align__(16) float Cs[4096];
  __shared__ float cred[4 * 64];
  __shared__ float fac[64];
  __shared__ int s_cnt[256];
  __shared__ int s_flag;

  const int tid = threadIdx.x;
  const int bid = blockIdx.x;
  const int lane = tid & 63;
  const int w = tid >> 6;
  const int tg = tid >> 2, q = tid & 3;
  const int row0 = bid * 256;

  // ---- prev_mask format detect (first 4096 bytes; deterministic) ----
  {
    uint4 v = ((const uint4*)pmask)[tid];
    int c = 0; u32 ww;
    ww = v.x; c += ((ww & 0xffu) != 0) + ((ww & 0xff00u) != 0) + ((ww & 0xff0000u) != 0) + ((ww & 0xff000000u) != 0);
    ww = v.y; c += ((ww & 0xffu) != 0) + ((ww & 0xff00u) != 0) + ((ww & 0xff0000u) != 0) + ((ww & 0xff000000u) != 0);
    ww = v.z; c += ((ww & 0xffu) != 0) + ((ww & 0xff00u) != 0) + ((ww & 0xff0000u) != 0) + ((ww & 0xff000000u) != 0);
    ww = v.w; c += ((ww & 0xffu) != 0) + ((ww & 0xff00u) != 0) + ((ww & 0xff0000u) != 0) + ((ww & 0xff000000u) != 0);
    s_cnt[tid] = c;
    __syncthreads();
    for (int s = 128; s; s >>= 1) { if (tid < s) s_cnt[tid] += s_cnt[tid + s]; __syncthreads(); }
    if (tid == 0) { int n = s_cnt[0]; s_flag = (n > 384) ? 0 : ((n > 192) ? 2 : 1); }
    __syncthreads();
  }

  float l[4][16], m[4][16];

  // ---- logits + center + softmax #1 (per group) ----
#pragma unroll
  for (int g = 0; g < 4; g++) {
    const int row = row0 + g * 64 + tg;
    const double* p0 = Lpart + (size_t)row * NE + q * 16;
    const double* p1 = p0 + (size_t)NT * NE;
#pragma unroll
    for (int i = 0; i < 4; i++) {
      float4 bv = *(const float4*)(b + q * 16 + i * 4);
      l[g][i * 4 + 0] = (float)(p0[i * 4 + 0] + p1[i * 4 + 0]) + bv.x;
      l[g][i * 4 + 1] = (float)(p0[i * 4 + 1] + p1[i * 4 + 1]) + bv.y;
      l[g][i * 4 + 2] = (float)(p0[i * 4 + 2] + p1[i * 4 + 2]) + bv.z;
      l[g][i * 4 + 3] = (float)(p0[i * 4 + 3] + p1[i * 4 + 3]) + bv.w;
    }
    float s = 0.f;
#pragma unroll
    for (int j = 0; j < 16; j++) s += l[g][j];
    s = warp4_sum(s);
    const float mean = s * (1.0f / 64.0f);
    float mx = -1e30f;
#pragma unroll
    for (int j = 0; j < 16; j++) { l[g][j] -= mean; mx = fmaxf(mx, l[g][j]); }
    mx = warp4_max(mx);
    float ps = 0.f;
#pragma unroll
    for (int j = 0; j < 16; j++) { m[g][j] = expf(l[g][j] - mx); ps += m[g][j]; }
    ps = warp4_sum(ps);
    const float inv = 1.0f / ps;
#pragma unroll
    for (int j = 0; j < 16; j++) m[g][j] *= inv;
  }

  // ---- gram partial over 256 tokens (4 staged groups) -> atomics ----
  {
    const int gi0 = (tid >> 4) * 4;
    const int gj0 = (tid & 15) * 4;
    float ga[4][4];
#pragma unroll
    for (int a = 0; a < 4; a++)
#pragma unroll
      for (int c = 0; c < 4; c++) ga[a][c] = 0.f;
#pragma unroll
    for (int g = 0; g < 4; g++) {
      __syncthreads();
#pragma unroll
      for (int i = 0; i < 4; i++)
        *(float4*)(ms + tg * 68 + q * 16 + i * 4) =
            make_float4(m[g][i * 4], m[g][i * 4 + 1], m[g][i * 4 + 2], m[g][i * 4 + 3]);
      __syncthreads();
      for (int t = 0; t < 64; t++) {
        float4 a = *(const float4*)(ms + t * 68 + gi0);
        float4 bb = *(const float4*)(ms + t * 68 + gj0);
        ga[0][0] = fmaf(a.x, bb.x, ga[0][0]); ga[0][1] = fmaf(a.x, bb.y, ga[0][1]);
        ga[0][2] = fmaf(a.x, bb.z, ga[0][2]); ga[0][3] = fmaf(a.x, bb.w, ga[0][3]);
        ga[1][0] = fmaf(a.y, bb.x, ga[1][0]); ga[1][1] = fmaf(a.y, bb.y, ga[1][1]);
        ga[1][2] = fmaf(a.y, bb.z, ga[1][2]); ga[1][3] = fmaf(a.y, bb.w, ga[1][3]);
        ga[2][0] = fmaf(a.z, bb.x, ga[2][0]); ga[2][1] = fmaf(a.z, bb.y, ga[2][1]);
        ga[2][2] = fmaf(a.z, bb.z, ga[2][2]); ga[2][3] = fmaf(a.z, bb.w, ga[2][3]);
        ga[3][0] = fmaf(a.w, bb.x, ga[3][0]); ga[3][1] = fmaf(a.w, bb.y, ga[3][1]);
        ga[3][2] = fmaf(a.w, bb.z, ga[3][2]); ga[3][3] = fmaf(a.w, bb.w, ga[3][3]);
      }
    }
#pragma unroll
    for (int ii = 0; ii < 4; ii++)
#pragma unroll
      for (int jj = 0; jj < 4; jj++)
        atomicAdd(CmAcc + (gi0 + ii) * 64 + gj0 + jj, to_fx(ga[ii][jj]));
  }
  gbar(ctr + 0, NB);

  // ---- load C (coherent), zero diag ----
#pragma unroll 4
  for (int i = 0; i < 16; i++) {
    int idx = tid + i * 256;
    float v = from_fx(aload_u64(CmAcc + idx));
    int r = idx >> 6, c = idx & 63;
    Cs[idx] = (r == c) ? 0.f : v;
  }

  // ---- correction + softmax #2 (per group, staged ms) ----
#pragma unroll
  for (int g = 0; g < 4; g++) {
    __syncthreads();
#pragma unroll
    for (int i = 0; i < 4; i++)
      *(float4*)(ms + tg * 68 + q * 16 + i * 4) =
          make_float4(m[g][i * 4], m[g][i * 4 + 1], m[g][i * 4 + 2], m[g][i * 4 + 3]);
    __syncthreads();
    float gv[16];
#pragma unroll
    for (int j = 0; j < 16; j++) gv[j] = 0.f;
    for (int f = 0; f < 64; f++) {
      float mf = ms[tg * 68 + f];
#pragma unroll
      for (int i = 0; i < 4; i++) {
        float4 cv = *(const float4*)(Cs + f * 64 + q * 16 + i * 4);
        gv[i * 4 + 0] = fmaf(mf, cv.x, gv[i * 4 + 0]);
        gv[i * 4 + 1] = fmaf(mf, cv.y, gv[i * 4 + 1]);
        gv[i * 4 + 2] = fmaf(mf, cv.z, gv[i * 4 + 2]);
        gv[i * 4 + 3] = fmaf(mf, cv.w, gv[i * 4 + 3]);
      }
    }
    float dot = 0.f;
#pragma unroll
    for (int j = 0; j < 16; j++) { gv[j] *= 4.f; dot += m[g][j] * gv[j]; }
    dot = warp4_sum(dot);
    float mx = -1e30f;
#pragma unroll
    for (int j = 0; j < 16; j++) {
      l[g][j] = l[g][j] - LTAX * (m[g][j] * (gv[j] - dot));
      mx = fmaxf(mx, l[g][j]);
    }
    mx = warp4_max(mx);
    float ps = 0.f;
#pragma unroll
    for (int j = 0; j < 16; j++) { m[g][j] = expf(l[g][j] - mx); ps += m[g][j]; }
    ps = warp4_sum(ps);
    const float inv = 1.0f / ps;
#pragma unroll
    for (int j = 0; j < 16; j++) m[g][j] *= inv;
  }

#define COLSUM_ADD(K) { \
    float cs[16]; \
    _Pragma("unroll") for (int j = 0; j < 16; j++) \
      cs[j] = m[0][j] + m[1][j] + m[2][j] + m[3][j]; \
    _Pragma("unroll") for (int j = 0; j < 16; j++) { \
      cs[j] += __shfl_xor(cs[j], 4);  cs[j] += __shfl_xor(cs[j], 8); \
      cs[j] += __shfl_xor(cs[j], 16); cs[j] += __shfl_xor(cs[j], 32); } \
    if ((lane >> 2) == 0) { \
      _Pragma("unroll") for (int j = 0; j < 16; j++) cred[w * 64 + lane * 16 + j] = cs[j]; \
    } \
    __syncthreads(); \
    if (tid < 64) \
      atomicAdd(colAcc + (K) * 64 + tid, \
                to_fx(cred[tid] + cred[64 + tid] + cred[128 + tid] + cred[192 + tid])); }

  // ---- Sinkhorn: 10 iterations ----
  COLSUM_ADD(0);
  gbar(ctr + 1, NB);
#pragma unroll 1
  for (int it = 0; it < 10; it++) {
    if (tid < 64) {
      double s = (double)aload_u64(colAcc + it * 64 + tid) * (1.0 / 4294967296.0);
      fac[tid] = (float)((1.0 / 256.0) / fmax(s, 1e-12));
    }
    __syncthreads();
#pragma unroll
    for (int g = 0; g < 4; g++) {
      float rs = 0.f;
#pragma unroll
      for (int j = 0; j < 16; j++) { m[g][j] *= fac[q * 16 + j]; rs += m[g][j]; }
      rs = warp4_sum(rs);
      const float inv = 1.0f / fmaxf(rs, 1e-12f);
#pragma unroll
      for (int j = 0; j < 16; j++) m[g][j] *= inv;
    }
    if (it < 9) {
      COLSUM_ADD(it + 1);
      gbar(ctr + 2 + it, NB);
    }
    __syncthreads();
  }

  // ---- damping + hysteresis + renorm + top-8 (per group) ----
  const int flag = s_flag;
  float* mout = out;
  float* kout = out + (size_t)NT * NE;
#pragma unroll
  for (int g = 0; g < 4; g++) {
    const int row = row0 + g * 64 + tg;
    float pv[16], mk[16];
#pragma unroll
    for (int i = 0; i < 4; i++) {
      float4 v = *(const float4*)(pp + (size_t)row * NE + q * 16 + i * 4);
      pv[i * 4 + 0] = v.x; pv[i * 4 + 1] = v.y; pv[i * 4 + 2] = v.z; pv[i * 4 + 3] = v.w;
    }
    if (flag == 0) {
      const u32* pb = (const u32*)pmask + row * 16 + q * 4;
#pragma unroll
      for (int i = 0; i < 4; i++) {
        u32 ww = pb[i];
        mk[i * 4 + 0] = (ww & 0xffu) ? 1.f : 0.f;
        mk[i * 4 + 1] = (ww & 0xff00u) ? 1.f : 0.f;
        mk[i * 4 + 2] = (ww & 0xff0000u) ? 1.f : 0.f;
        mk[i * 4 + 3] = (ww & 0xff000000u) ? 1.f : 0.f;
      }
    } else if (flag == 1) {
      const int* pb = (const int*)pmask + (size_t)row * NE + q * 16;
#pragma unroll
      for (int j = 0; j < 16; j++) mk[j] = pb[j] ? 1.f : 0.f;
    } else {
      const float* pb = (const float*)pmask + (size_t)row * NE + q * 16;
#pragma unroll
      for (int j = 0; j < 16; j++) mk[j] = (pb[j] != 0.f) ? 1.f : 0.f;
    }
    float msum = 0.f;
#pragma unroll
    for (int j = 0; j < 16; j++) msum += mk[j];
    msum = warp4_sum(msum);
    const float hscale = HYST / fmaxf(msum, 1.0f);
    float v[16];
    float s = 0.f;
#pragma unroll
    for (int j = 0; j < 16; j++) {
      float base = (1.f - ALPHA) * pv[j] + ALPHA * m[g][j];
      v[j] = (1.f - HYST) * base + hscale * mk[j];
      s += v[j];
    }
    s = warp4_sum(s);
    const float inv = 1.0f / fmaxf(s, 1e-12f);
#pragma unroll
    for (int j = 0; j < 16; j++) v[j] *= inv;

#pragma unroll
    for (int i = 0; i < 4; i++)
      *(float4*)(mout + (size_t)row * NE + q * 16 + i * 4) =
          make_float4(v[i * 4], v[i * 4 + 1], v[i * 4 + 2], v[i * 4 + 3]);

    int cnt[16];
#pragma unroll
    for (int j = 0; j < 16; j++) cnt[j] = 0;
    const int base = lane & ~3;
#pragma unroll
    for (int oq = 0; oq < 4; oq++) {
#pragma unroll
      for (int j2 = 0; j2 < 16; j2++) {
        float ov = __shfl(v[j2], base + oq, 64);
        int oe = oq * 16 + j2;
#pragma unroll
        for (int j = 0; j < 16; j++) {
          int me = q * 16 + j;
          if (ov > v[j] || (ov == v[j] && oe < me)) cnt[j]++;
        }
      }
    }
#pragma unroll
    for (int i = 0; i < 4; i++)
      *(float4*)(kout + (size_t)row * NE + q * 16 + i * 4) =
          make_float4(cnt[i * 4] < TOPK ? 1.f : 0.f, cnt[i * 4 + 1] < TOPK ? 1.f : 0.f,
                      cnt[i * 4 + 2] < TOPK ? 1.f : 0.f, cnt[i * 4 + 3] < TOPK ? 1.f : 0.f);
  }
}

extern "C" void kernel_launch(void* const* d_in, const int* in_sizes, int n_in,
                              void* d_out, int out_size, void* d_ws, size_t ws_size,
                              hipStream_t stream) {
  const float* x = (const float*)d_in[0];
  const float* W = (const float*)d_in[1];
  const float* b = (const float*)d_in[2];
  const float* pp = (const float*)d_in[3];
  const void* pmask = d_in[4];
  float* out = (float*)d_out;

  unsigned char* wsb = (unsigned char*)d_ws;
  u16* Wh = (u16*)(wsb);                          // 256 KB
  u16* Wm = (u16*)(wsb + 262144);                 // 256 KB
  u16* Wl = (u16*)(wsb + 524288);                 // 256 KB
  double* Lpart = (double*)(wsb + 786432);        // 16 MB
  u64* CmAcc = (u64*)(wsb + 17563648);            // 4096 u64 = 32 KB
  u64* colAcc = (u64*)(wsb + 17596416);           // 10*64 u64 = 5 KB
  u32* ctr = (u32*)(wsb + 17601536);              // 16 u32

  hipMemsetAsync(wsb + 17563648, 0, 37952, stream);
  k_wsplit3<<<128, 256, 0, stream>>>(W, Wh, Wm, Wl);
  k_gemm<<<512, 256, 0, stream>>>(x, Wh, Wm, Wl, Lpart);

  void* args[] = {(void*)&Lpart, (void*)&b, (void*)&pp, (void*)&pmask,
                  (void*)&CmAcc, (void*)&colAcc, (void*)&ctr, (void*)&out};
  hipLaunchCooperativeKernel((void*)k_tail, dim3(64), dim3(256), args, 0, stream);
}

// Round 10
// 292.666 us; speedup vs baseline: 2.8978x; 1.0301x over previous
//
#include <hip/hip_runtime.h>
#include <hip/hip_cooperative_groups.h>
#include <math.h>

#define NT 16384
#define DM 2048
#define NE 64
#define TOPK 8
#define LTAX 0.04f
#define HYST 0.1f
#define ALPHA 0.7f

typedef unsigned int u32;
typedef unsigned short u16;
typedef unsigned long long u64;
typedef __attribute__((ext_vector_type(8))) short bf16x8;
typedef __attribute__((ext_vector_type(4))) float f32x4;

__device__ __forceinline__ float warp4_sum(float v) {
  v += __shfl_xor(v, 1); v += __shfl_xor(v, 2); return v;
}
__device__ __forceinline__ float warp4_max(float v) {
  v = fmaxf(v, __shfl_xor(v, 1)); v = fmaxf(v, __shfl_xor(v, 2)); return v;
}
__device__ __forceinline__ u16 f2bf(float f) {   // RNE f32->bf16
  u32 u = __float_as_uint(f);
  return (u16)((u + 0x7fffu + ((u >> 16) & 1u)) >> 16);
}
__device__ __forceinline__ float bf2f(u16 h) { return __uint_as_float(((u32)h) << 16); }

__device__ __forceinline__ void split3(float a, short& h, short& m, short& l) {
  u16 hh = f2bf(a);  float r1 = a - bf2f(hh);     // exact (Sterbenz)
  u16 mm = f2bf(r1); float r2 = r1 - bf2f(mm);    // exact
  h = (short)hh; m = (short)mm; l = (short)f2bf(r2);
}

// fixed-point 2^32: exact-commutative integer atomics => deterministic
__device__ __forceinline__ u64 to_fx(float v) {
  return (u64)__double2ll_rn((double)v * 4294967296.0);
}
__device__ __forceinline__ u64 aload_u64(const u64* p) {
  return __hip_atomic_load(p, __ATOMIC_RELAXED, __HIP_MEMORY_SCOPE_AGENT);
}
// 2-level arrival tree + relaxed polling. Counters per phase: subs[16] (one
// 64B line) + root (next 64B line). Phase stride = 32 u32.
__device__ __forceinline__ void gbar(u32* base, int phase, int bid) {
  __syncthreads();
  if (threadIdx.x == 0) {
    u32* subs = base + phase * 32;
    u32* root = subs + 16;
    const int grp = bid & 15;
    u32 old = __hip_atomic_fetch_add(subs + grp, 1u, __ATOMIC_RELEASE, __HIP_MEMORY_SCOPE_AGENT);
    if (old == 15u)
      __hip_atomic_fetch_add(root, 1u, __ATOMIC_RELEASE, __HIP_MEMORY_SCOPE_AGENT);
    while (__hip_atomic_load(root, __ATOMIC_RELAXED, __HIP_MEMORY_SCOPE_AGENT) < 16u)
      __builtin_amdgcn_s_sleep(4);
    (void)__hip_atomic_load(root, __ATOMIC_ACQUIRE, __HIP_MEMORY_SCOPE_AGENT);
  }
  __syncthreads();
}

// ---------------- K0: W -> bf16 hi/mid/lo ----------------------------------
__global__ void k_wsplit3(const float* __restrict__ W, u16* __restrict__ Wh,
                          u16* __restrict__ Wm, u16* __restrict__ Wl) {
  int idx = (blockIdx.x * 256 + threadIdx.x) * 4;
  float4 v = *(const float4*)(W + idx);
  short h[4], m[4], l[4];
  split3(v.x, h[0], m[0], l[0]);
  split3(v.y, h[1], m[1], l[1]);
  split3(v.z, h[2], m[2], l[2]);
  split3(v.w, h[3], m[3], l[3]);
  *(ushort4*)(Wh + idx) = make_ushort4((u16)h[0], (u16)h[1], (u16)h[2], (u16)h[3]);
  *(ushort4*)(Wm + idx) = make_ushort4((u16)m[0], (u16)m[1], (u16)m[2], (u16)m[3]);
  *(ushort4*)(Wl + idx) = make_ushort4((u16)l[0], (u16)l[1], (u16)l[2], (u16)l[3]);
}

// ---------------- K1: MFMA GEMM, split-K=2, f64 partials (unchanged) --------
__launch_bounds__(256, 2)
__global__ void k_gemm(const float* __restrict__ x, const u16* __restrict__ Whg,
                       const u16* __restrict__ Wmg, const u16* __restrict__ Wlg,
                       double* __restrict__ Lpart) {
  __shared__ __align__(16) u16 XS[30720];   // 6 arrays x 2 buf x [64][40]
  const int tid = threadIdx.x;
  const int bid = blockIdx.x;
  const int tile = bid >> 1, ks = bid & 1;
  const int row0 = tile * 64;
  const int k0 = ks * 1024;
  const int lane = tid & 63, w = tid >> 6, l15 = lane & 15, l4 = lane >> 4;
  const int srow = tid >> 2, c8 = (tid & 3) * 8;
  const int stoff = srow * 40 + c8;

  f32x4 accA[4], accB[4];
  double accD[4][4];
#pragma unroll
  for (int eb = 0; eb < 4; eb++) {
    accA[eb] = (f32x4)0.f; accB[eb] = (f32x4)0.f;
#pragma unroll
    for (int r = 0; r < 4; r++) accD[eb][r] = 0.0;
  }

  float4 xq0, xq1;
  uint4 whv, wmv, wlv;
  const float* xrowp = x + (size_t)(row0 + srow) * DM + k0 + c8;
  const u16* whp = Whg + srow * DM + k0 + c8;
  const u16* wmp = Wmg + srow * DM + k0 + c8;
  const u16* wlp = Wlg + srow * DM + k0 + c8;

#define LOADCH(KC) { \
    xq0 = *(const float4*)(xrowp + (KC)); \
    xq1 = *(const float4*)(xrowp + (KC) + 4); \
    whv = *(const uint4*)(whp + (KC)); \
    wmv = *(const uint4*)(wmp + (KC)); \
    wlv = *(const uint4*)(wlp + (KC)); }

#define WRITECH(B) { \
    short ha[8], ma[8], la[8]; \
    split3(xq0.x, ha[0], ma[0], la[0]); \
    split3(xq0.y, ha[1], ma[1], la[1]); \
    split3(xq0.z, ha[2], ma[2], la[2]); \
    split3(xq0.w, ha[3], ma[3], la[3]); \
    split3(xq1.x, ha[4], ma[4], la[4]); \
    split3(xq1.y, ha[5], ma[5], la[5]); \
    split3(xq1.z, ha[6], ma[6], la[6]); \
    split3(xq1.w, ha[7], ma[7], la[7]); \
    bf16x8 xh8, xm8, xl8; \
    _Pragma("unroll") \
    for (int z = 0; z < 8; z++) { xh8[z] = ha[z]; xm8[z] = ma[z]; xl8[z] = la[z]; } \
    *(bf16x8*)(XS + 0     + (B) * 2560 + stoff) = xh8; \
    *(bf16x8*)(XS + 5120  + (B) * 2560 + stoff) = xm8; \
    *(bf16x8*)(XS + 10240 + (B) * 2560 + stoff) = xl8; \
    *(uint4*)(XS + 15360 + (B) * 2560 + stoff) = whv; \
    *(uint4*)(XS + 20480 + (B) * 2560 + stoff) = wmv; \
    *(uint4*)(XS + 25600 + (B) * 2560 + stoff) = wlv; }

#define COMPUTECH(B) { \
    const int ar = (w * 16 + l15) * 40 + l4 * 8; \
    bf16x8 ah = *(const bf16x8*)(XS + 0     + (B) * 2560 + ar); \
    bf16x8 am = *(const bf16x8*)(XS + 5120  + (B) * 2560 + ar); \
    bf16x8 al = *(const bf16x8*)(XS + 10240 + (B) * 2560 + ar); \
    _Pragma("unroll") \
    for (int eb = 0; eb < 4; eb++) { \
      const int br = (eb * 16 + l15) * 40 + l4 * 8; \
      bf16x8 bh = *(const bf16x8*)(XS + 15360 + (B) * 2560 + br); \
      bf16x8 bm = *(const bf16x8*)(XS + 20480 + (B) * 2560 + br); \
      bf16x8 bl = *(const bf16x8*)(XS + 25600 + (B) * 2560 + br); \
      accA[eb] = __builtin_amdgcn_mfma_f32_16x16x32_bf16(ah, bh, accA[eb], 0, 0, 0); \
      accB[eb] = __builtin_amdgcn_mfma_f32_16x16x32_bf16(ah, bm, accB[eb], 0, 0, 0); \
      accB[eb] = __builtin_amdgcn_mfma_f32_16x16x32_bf16(am, bh, accB[eb], 0, 0, 0); \
      accB[eb] = __builtin_amdgcn_mfma_f32_16x16x32_bf16(am, bm, accB[eb], 0, 0, 0); \
      accB[eb] = __builtin_amdgcn_mfma_f32_16x16x32_bf16(ah, bl, accB[eb], 0, 0, 0); \
      accB[eb] = __builtin_amdgcn_mfma_f32_16x16x32_bf16(al, bh, accB[eb], 0, 0, 0); \
    } }

  LOADCH(0);
  WRITECH(0);
  __syncthreads();
#pragma unroll 1
  for (int t = 0; t < 32; t++) {
    if (t < 31) LOADCH((t + 1) * 32);
    COMPUTECH(t & 1);
    if ((t & 7) == 7) {
#pragma unroll
      for (int eb = 0; eb < 4; eb++) {
#pragma unroll
        for (int r = 0; r < 4; r++)
          accD[eb][r] += (double)accA[eb][r] + (double)accB[eb][r];
        accA[eb] = (f32x4)0.f; accB[eb] = (f32x4)0.f;
      }
    }
    if (t < 31) WRITECH((t + 1) & 1);
    __syncthreads();
  }

  double* outp = Lpart + (size_t)ks * NT * NE;
#pragma unroll
  for (int eb = 0; eb < 4; eb++)
#pragma unroll
    for (int r = 0; r < 4; r++) {
      int trow = w * 16 + l4 * 4 + r;
      outp[(size_t)(row0 + trow) * NE + eb * 16 + l15] = accD[eb][r];
    }
}

// ---------------- K2: cooperative tail, 256 blocks, tree barriers -----------
__launch_bounds__(256, 1)
__global__ void k_tail(const double* __restrict__ Lpart, const float* __restrict__ b,
                       const float* __restrict__ pp, const void* __restrict__ pmask,
                       u64* __restrict__ CmAcc, u64* __restrict__ colAcc,
                       u32* __restrict__ ctr, float* __restrict__ out) {
  __shared__ __align__(16) float ms[64 * 68];
  __shared__ __align__(16) float Cs[4096];
  __shared__ float cred[4 * 64];
  __shared__ float fac[64];
  __shared__ int s_cnt[256];
  __shared__ int s_flag;

  const int tid = threadIdx.x;
  const int bid = blockIdx.x;
  const int lane = tid & 63;
  const int w = tid >> 6;
  const int row0 = bid * 64;

  // ---- prev_mask format detect (first 4096 bytes; deterministic) ----
  {
    uint4 v = ((const uint4*)pmask)[tid];
    int c = 0; u32 ww;
    ww = v.x; c += ((ww & 0xffu) != 0) + ((ww & 0xff00u) != 0) + ((ww & 0xff0000u) != 0) + ((ww & 0xff000000u) != 0);
    ww = v.y; c += ((ww & 0xffu) != 0) + ((ww & 0xff00u) != 0) + ((ww & 0xff0000u) != 0) + ((ww & 0xff000000u) != 0);
    ww = v.z; c += ((ww & 0xffu) != 0) + ((ww & 0xff00u) != 0) + ((ww & 0xff0000u) != 0) + ((ww & 0xff000000u) != 0);
    ww = v.w; c += ((ww & 0xffu) != 0) + ((ww & 0xff00u) != 0) + ((ww & 0xff0000u) != 0) + ((ww & 0xff000000u) != 0);
    s_cnt[tid] = c;
    __syncthreads();
    for (int s = 128; s; s >>= 1) { if (tid < s) s_cnt[tid] += s_cnt[tid + s]; __syncthreads(); }
    if (tid == 0) { int n = s_cnt[0]; s_flag = (n > 384) ? 0 : ((n > 192) ? 2 : 1); }
    __syncthreads();
  }

  // ---- logits from f64 partials + bias; center; softmax #1 ----
  const int tg = tid >> 2, q = tid & 3;
  const int row = row0 + tg;
  float l[16], m[16];
  {
    const double* p0 = Lpart + (size_t)row * NE + q * 16;
    const double* p1 = p0 + (size_t)NT * NE;
#pragma unroll
    for (int i = 0; i < 4; i++) {
      float4 bv = *(const float4*)(b + q * 16 + i * 4);
      l[i * 4 + 0] = (float)(p0[i * 4 + 0] + p1[i * 4 + 0]) + bv.x;
      l[i * 4 + 1] = (float)(p0[i * 4 + 1] + p1[i * 4 + 1]) + bv.y;
      l[i * 4 + 2] = (float)(p0[i * 4 + 2] + p1[i * 4 + 2]) + bv.z;
      l[i * 4 + 3] = (float)(p0[i * 4 + 3] + p1[i * 4 + 3]) + bv.w;
    }
    float s = 0.f;
#pragma unroll
    for (int j = 0; j < 16; j++) s += l[j];
    s = warp4_sum(s);
    const float mean = s * (1.0f / 64.0f);
    float mx = -1e30f;
#pragma unroll
    for (int j = 0; j < 16; j++) { l[j] -= mean; mx = fmaxf(mx, l[j]); }
    mx = warp4_max(mx);
    float ps = 0.f;
#pragma unroll
    for (int j = 0; j < 16; j++) { m[j] = expf(l[j] - mx); ps += m[j]; }
    ps = warp4_sum(ps);
    const float inv = 1.0f / ps;
#pragma unroll
    for (int j = 0; j < 16; j++) m[j] *= inv;
#pragma unroll
    for (int i = 0; i < 4; i++)
      *(float4*)(ms + tg * 68 + q * 16 + i * 4) =
          make_float4(m[i * 4], m[i * 4 + 1], m[i * 4 + 2], m[i * 4 + 3]);
  }
  __syncthreads();

  // ---- gram partial -> slotted fixed-point atomics (4 slots) ----
  {
    const int gi0 = (tid >> 4) * 4;
    const int gj0 = (tid & 15) * 4;
    float ga[4][4];
#pragma unroll
    for (int a = 0; a < 4; a++)
#pragma unroll
      for (int c = 0; c < 4; c++) ga[a][c] = 0.f;
    for (int t = 0; t < 64; t++) {
      float4 a = *(const float4*)(ms + t * 68 + gi0);
      float4 bb = *(const float4*)(ms + t * 68 + gj0);
      ga[0][0] = fmaf(a.x, bb.x, ga[0][0]); ga[0][1] = fmaf(a.x, bb.y, ga[0][1]);
      ga[0][2] = fmaf(a.x, bb.z, ga[0][2]); ga[0][3] = fmaf(a.x, bb.w, ga[0][3]);
      ga[1][0] = fmaf(a.y, bb.x, ga[1][0]); ga[1][1] = fmaf(a.y, bb.y, ga[1][1]);
      ga[1][2] = fmaf(a.y, bb.z, ga[1][2]); ga[1][3] = fmaf(a.y, bb.w, ga[1][3]);
      ga[2][0] = fmaf(a.z, bb.x, ga[2][0]); ga[2][1] = fmaf(a.z, bb.y, ga[2][1]);
      ga[2][2] = fmaf(a.z, bb.z, ga[2][2]); ga[2][3] = fmaf(a.z, bb.w, ga[2][3]);
      ga[3][0] = fmaf(a.w, bb.x, ga[3][0]); ga[3][1] = fmaf(a.w, bb.y, ga[3][1]);
      ga[3][2] = fmaf(a.w, bb.z, ga[3][2]); ga[3][3] = fmaf(a.w, bb.w, ga[3][3]);
    }
    u64* slot = CmAcc + (size_t)(bid & 3) * 4096;
#pragma unroll
    for (int ii = 0; ii < 4; ii++)
#pragma unroll
      for (int jj = 0; jj < 4; jj++)
        atomicAdd(slot + (gi0 + ii) * 64 + gj0 + jj, to_fx(ga[ii][jj]));
  }
  gbar(ctr, 0, bid);

  // ---- load C (sum 4 slots, coherent), zero diag ----
#pragma unroll 4
  for (int i = 0; i < 16; i++) {
    int idx = tid + i * 256;
    u64 s = aload_u64(CmAcc + idx) + aload_u64(CmAcc + 4096 + idx) +
            aload_u64(CmAcc + 8192 + idx) + aload_u64(CmAcc + 12288 + idx);
    float v = (float)((double)s * (1.0 / 4294967296.0));
    int r = idx >> 6, c = idx & 63;
    Cs[idx] = (r == c) ? 0.f : v;
  }
  __syncthreads();

  // ---- correction + softmax #2 ----
  {
    float g[16];
#pragma unroll
    for (int j = 0; j < 16; j++) g[j] = 0.f;
    for (int f = 0; f < 64; f++) {
      float mf = ms[tg * 68 + f];
#pragma unroll
      for (int i = 0; i < 4; i++) {
        float4 cv = *(const float4*)(Cs + f * 64 + q * 16 + i * 4);
        g[i * 4 + 0] = fmaf(mf, cv.x, g[i * 4 + 0]);
        g[i * 4 + 1] = fmaf(mf, cv.y, g[i * 4 + 1]);
        g[i * 4 + 2] = fmaf(mf, cv.z, g[i * 4 + 2]);
        g[i * 4 + 3] = fmaf(mf, cv.w, g[i * 4 + 3]);
      }
    }
    float dot = 0.f;
#pragma unroll
    for (int j = 0; j < 16; j++) { g[j] *= 4.f; dot += m[j] * g[j]; }
    dot = warp4_sum(dot);
    float mx = -1e30f;
#pragma unroll
    for (int j = 0; j < 16; j++) {
      l[j] = l[j] - LTAX * (m[j] * (g[j] - dot));
      mx = fmaxf(mx, l[j]);
    }
    mx = warp4_max(mx);
    float ps = 0.f;
#pragma unroll
    for (int j = 0; j < 16; j++) { m[j] = expf(l[j] - mx); ps += m[j]; }
    ps = warp4_sum(ps);
    const float inv = 1.0f / ps;
#pragma unroll
    for (int j = 0; j < 16; j++) m[j] *= inv;
  }

#define COLSUM_ADD(K) { \
    float cs[16]; \
    _Pragma("unroll") for (int j = 0; j < 16; j++) cs[j] = m[j]; \
    _Pragma("unroll") for (int j = 0; j < 16; j++) { \
      cs[j] += __shfl_xor(cs[j], 4);  cs[j] += __shfl_xor(cs[j], 8); \
      cs[j] += __shfl_xor(cs[j], 16); cs[j] += __shfl_xor(cs[j], 32); } \
    if ((lane >> 2) == 0) { \
      _Pragma("unroll") for (int j = 0; j < 16; j++) cred[w * 64 + lane * 16 + j] = cs[j]; \
    } \
    __syncthreads(); \
    if (tid < 64) \
      atomicAdd(colAcc + ((size_t)(K) * 16 + (bid & 15)) * 64 + tid, \
                to_fx(cred[tid] + cred[64 + tid] + cred[128 + tid] + cred[192 + tid])); }

  // ---- Sinkhorn: 10 iterations ----
  COLSUM_ADD(0);
  gbar(ctr, 1, bid);
#pragma unroll 1
  for (int it = 0; it < 10; it++) {
    if (tid < 64) {
      const u64* base = colAcc + (size_t)it * 16 * 64 + tid;
      u64 s = 0;
#pragma unroll
      for (int sl = 0; sl < 16; sl++) s += aload_u64(base + sl * 64);
      double d = (double)s * (1.0 / 4294967296.0);
      fac[tid] = (float)((1.0 / 256.0) / fmax(d, 1e-12));
    }
    __syncthreads();
    float rs = 0.f;
#pragma unroll
    for (int j = 0; j < 16; j++) { m[j] *= fac[q * 16 + j]; rs += m[j]; }
    rs = warp4_sum(rs);
    const float inv = 1.0f / fmaxf(rs, 1e-12f);
#pragma unroll
    for (int j = 0; j < 16; j++) m[j] *= inv;
    if (it < 9) {
      COLSUM_ADD(it + 1);
      gbar(ctr, 2 + it, bid);
    }
    __syncthreads();
  }

  // ---- damping + hysteresis + renorm + top-8 ----
  {
    const int flag = s_flag;
    float pv[16], mk[16];
#pragma unroll
    for (int i = 0; i < 4; i++) {
      float4 v = *(const float4*)(pp + (size_t)row * NE + q * 16 + i * 4);
      pv[i * 4 + 0] = v.x; pv[i * 4 + 1] = v.y; pv[i * 4 + 2] = v.z; pv[i * 4 + 3] = v.w;
    }
    if (flag == 0) {
      const u32* pb = (const u32*)pmask + row * 16 + q * 4;
#pragma unroll
      for (int i = 0; i < 4; i++) {
        u32 ww = pb[i];
        mk[i * 4 + 0] = (ww & 0xffu) ? 1.f : 0.f;
        mk[i * 4 + 1] = (ww & 0xff00u) ? 1.f : 0.f;
        mk[i * 4 + 2] = (ww & 0xff0000u) ? 1.f : 0.f;
        mk[i * 4 + 3] = (ww & 0xff000000u) ? 1.f : 0.f;
      }
    } else if (flag == 1) {
      const int* pb = (const int*)pmask + (size_t)row * NE + q * 16;
#pragma unroll
      for (int j = 0; j < 16; j++) mk[j] = pb[j] ? 1.f : 0.f;
    } else {
      const float* pb = (const float*)pmask + (size_t)row * NE + q * 16;
#pragma unroll
      for (int j = 0; j < 16; j++) mk[j] = (pb[j] != 0.f) ? 1.f : 0.f;
    }
    float msum = 0.f;
#pragma unroll
    for (int j = 0; j < 16; j++) msum += mk[j];
    msum = warp4_sum(msum);
    const float hscale = HYST / fmaxf(msum, 1.0f);
    float v[16];
    float s = 0.f;
#pragma unroll
    for (int j = 0; j < 16; j++) {
      float base = (1.f - ALPHA) * pv[j] + ALPHA * m[j];
      v[j] = (1.f - HYST) * base + hscale * mk[j];
      s += v[j];
    }
    s = warp4_sum(s);
    const float inv = 1.0f / fmaxf(s, 1e-12f);
#pragma unroll
    for (int j = 0; j < 16; j++) v[j] *= inv;

    float* mout = out;
    float* kout = out + (size_t)NT * NE;
#pragma unroll
    for (int i = 0; i < 4; i++)
      *(float4*)(mout + (size_t)row * NE + q * 16 + i * 4) =
          make_float4(v[i * 4], v[i * 4 + 1], v[i * 4 + 2], v[i * 4 + 3]);

    int cnt[16];
#pragma unroll
    for (int j = 0; j < 16; j++) cnt[j] = 0;
    const int base = lane & ~3;
#pragma unroll
    for (int oq = 0; oq < 4; oq++) {
#pragma unroll
      for (int j2 = 0; j2 < 16; j2++) {
        float ov = __shfl(v[j2], base + oq, 64);
        int oe = oq * 16 + j2;
#pragma unroll
        for (int j = 0; j < 16; j++) {
          int me = q * 16 + j;
          if (ov > v[j] || (ov == v[j] && oe < me)) cnt[j]++;
        }
      }
    }
#pragma unroll
    for (int i = 0; i < 4; i++)
      *(float4*)(kout + (size_t)row * NE + q * 16 + i * 4) =
          make_float4(cnt[i * 4] < TOPK ? 1.f : 0.f, cnt[i * 4 + 1] < TOPK ? 1.f : 0.f,
                      cnt[i * 4 + 2] < TOPK ? 1.f : 0.f, cnt[i * 4 + 3] < TOPK ? 1.f : 0.f);
  }
}

extern "C" void kernel_launch(void* const* d_in, const int* in_sizes, int n_in,
                              void* d_out, int out_size, void* d_ws, size_t ws_size,
                              hipStream_t stream) {
  const float* x = (const float*)d_in[0];
  const float* W = (const float*)d_in[1];
  const float* b = (const float*)d_in[2];
  const float* pp = (const float*)d_in[3];
  const void* pmask = d_in[4];
  float* out = (float*)d_out;

  unsigned char* wsb = (unsigned char*)d_ws;
  u16* Wh = (u16*)(wsb);                          // 256 KB
  u16* Wm = (u16*)(wsb + 262144);                 // 256 KB
  u16* Wl = (u16*)(wsb + 524288);                 // 256 KB
  double* Lpart = (double*)(wsb + 786432);        // 16 MB -> ends 17563648
  u64* CmAcc = (u64*)(wsb + 17563648);            // 4 slots * 4096 u64 = 128 KB
  u64* colAcc = (u64*)(wsb + 17694720);           // 10 * 16 * 64 u64 = 80 KB
  u32* ctr = (u32*)(wsb + 17776640);              // 11 phases * 32 u32 = 1408 B

  // zero accumulators + barrier counters (graph-capture safe)
  hipMemsetAsync(wsb + 17563648, 0, 214400, stream);
  k_wsplit3<<<128, 256, 0, stream>>>(W, Wh, Wm, Wl);
  k_gemm<<<512, 256, 0, stream>>>(x, Wh, Wm, Wl, Lpart);

  void* args[] = {(void*)&Lpart, (void*)&b, (void*)&pp, (void*)&pmask,
                  (void*)&CmAcc, (void*)&colAcc, (void*)&ctr, (void*)&out};
  hipLaunchCooperativeKernel((void*)k_tail, dim3(256), dim3(256), args, 0, stream);
}

// Round 11
// 181.310 us; speedup vs baseline: 4.6775x; 1.6142x over previous
//
#include <hip/hip_runtime.h>
#include <math.h>

#define NT 16384
#define DM 2048
#define NE 64
#define TOPK 8
#define LTAX 0.04f
#define HYST 0.1f
#define ALPHA 0.7f

typedef unsigned int u32;
typedef unsigned short u16;
typedef unsigned long long u64;
typedef __attribute__((ext_vector_type(8))) short bf16x8;
typedef __attribute__((ext_vector_type(4))) float f32x4;

__device__ __forceinline__ float warp4_sum(float v) {
  v += __shfl_xor(v, 1); v += __shfl_xor(v, 2); return v;
}
__device__ __forceinline__ float warp4_max(float v) {
  v = fmaxf(v, __shfl_xor(v, 1)); v = fmaxf(v, __shfl_xor(v, 2)); return v;
}
__device__ __forceinline__ u16 f2bf(float f) {   // RNE f32->bf16
  u32 u = __float_as_uint(f);
  return (u16)((u + 0x7fffu + ((u >> 16) & 1u)) >> 16);
}
__device__ __forceinline__ float bf2f(u16 h) { return __uint_as_float(((u32)h) << 16); }

__device__ __forceinline__ void split3(float a, short& h, short& m, short& l) {
  u16 hh = f2bf(a);  float r1 = a - bf2f(hh);     // exact (Sterbenz)
  u16 mm = f2bf(r1); float r2 = r1 - bf2f(mm);    // exact
  h = (short)hh; m = (short)mm; l = (short)f2bf(r2);
}

// fixed-point 2^32: exact-commutative integer atomics => deterministic
__device__ __forceinline__ u64 to_fx(float v) {
  return (u64)__double2ll_rn((double)v * 4294967296.0);
}

// ---------------- K0: W -> bf16 hi/mid/lo ----------------------------------
__global__ void k_wsplit3(const float* __restrict__ W, u16* __restrict__ Wh,
                          u16* __restrict__ Wm, u16* __restrict__ Wl) {
  int idx = (blockIdx.x * 256 + threadIdx.x) * 4;
  float4 v = *(const float4*)(W + idx);
  short h[4], m[4], l[4];
  split3(v.x, h[0], m[0], l[0]);
  split3(v.y, h[1], m[1], l[1]);
  split3(v.z, h[2], m[2], l[2]);
  split3(v.w, h[3], m[3], l[3]);
  *(ushort4*)(Wh + idx) = make_ushort4((u16)h[0], (u16)h[1], (u16)h[2], (u16)h[3]);
  *(ushort4*)(Wm + idx) = make_ushort4((u16)m[0], (u16)m[1], (u16)m[2], (u16)m[3]);
  *(ushort4*)(Wl + idx) = make_ushort4((u16)l[0], (u16)l[1], (u16)l[2], (u16)l[3]);
}

// ---------------- K1: MFMA GEMM, split-K=2, f64 partials (proven) -----------
__launch_bounds__(256, 2)
__global__ void k_gemm(const float* __restrict__ x, const u16* __restrict__ Whg,
                       const u16* __restrict__ Wmg, const u16* __restrict__ Wlg,
                       double* __restrict__ Lpart) {
  __shared__ __align__(16) u16 XS[30720];   // 6 arrays x 2 buf x [64][40]
  const int tid = threadIdx.x;
  const int bid = blockIdx.x;
  const int tile = bid >> 1, ks = bid & 1;
  const int row0 = tile * 64;
  const int k0 = ks * 1024;
  const int lane = tid & 63, w = tid >> 6, l15 = lane & 15, l4 = lane >> 4;
  const int srow = tid >> 2, c8 = (tid & 3) * 8;
  const int stoff = srow * 40 + c8;

  f32x4 accA[4], accB[4];
  double accD[4][4];
#pragma unroll
  for (int eb = 0; eb < 4; eb++) {
    accA[eb] = (f32x4)0.f; accB[eb] = (f32x4)0.f;
#pragma unroll
    for (int r = 0; r < 4; r++) accD[eb][r] = 0.0;
  }

  float4 xq0, xq1;
  uint4 whv, wmv, wlv;
  const float* xrowp = x + (size_t)(row0 + srow) * DM + k0 + c8;
  const u16* whp = Whg + srow * DM + k0 + c8;
  const u16* wmp = Wmg + srow * DM + k0 + c8;
  const u16* wlp = Wlg + srow * DM + k0 + c8;

#define LOADCH(KC) { \
    xq0 = *(const float4*)(xrowp + (KC)); \
    xq1 = *(const float4*)(xrowp + (KC) + 4); \
    whv = *(const uint4*)(whp + (KC)); \
    wmv = *(const uint4*)(wmp + (KC)); \
    wlv = *(const uint4*)(wlp + (KC)); }

#define WRITECH(B) { \
    short ha[8], ma[8], la[8]; \
    split3(xq0.x, ha[0], ma[0], la[0]); \
    split3(xq0.y, ha[1], ma[1], la[1]); \
    split3(xq0.z, ha[2], ma[2], la[2]); \
    split3(xq0.w, ha[3], ma[3], la[3]); \
    split3(xq1.x, ha[4], ma[4], la[4]); \
    split3(xq1.y, ha[5], ma[5], la[5]); \
    split3(xq1.z, ha[6], ma[6], la[6]); \
    split3(xq1.w, ha[7], ma[7], la[7]); \
    bf16x8 xh8, xm8, xl8; \
    _Pragma("unroll") \
    for (int z = 0; z < 8; z++) { xh8[z] = ha[z]; xm8[z] = ma[z]; xl8[z] = la[z]; } \
    *(bf16x8*)(XS + 0     + (B) * 2560 + stoff) = xh8; \
    *(bf16x8*)(XS + 5120  + (B) * 2560 + stoff) = xm8; \
    *(bf16x8*)(XS + 10240 + (B) * 2560 + stoff) = xl8; \
    *(uint4*)(XS + 15360 + (B) * 2560 + stoff) = whv; \
    *(uint4*)(XS + 20480 + (B) * 2560 + stoff) = wmv; \
    *(uint4*)(XS + 25600 + (B) * 2560 + stoff) = wlv; }

#define COMPUTECH(B) { \
    const int ar = (w * 16 + l15) * 40 + l4 * 8; \
    bf16x8 ah = *(const bf16x8*)(XS + 0     + (B) * 2560 + ar); \
    bf16x8 am = *(const bf16x8*)(XS + 5120  + (B) * 2560 + ar); \
    bf16x8 al = *(const bf16x8*)(XS + 10240 + (B) * 2560 + ar); \
    _Pragma("unroll") \
    for (int eb = 0; eb < 4; eb++) { \
      const int br = (eb * 16 + l15) * 40 + l4 * 8; \
      bf16x8 bh = *(const bf16x8*)(XS + 15360 + (B) * 2560 + br); \
      bf16x8 bm = *(const bf16x8*)(XS + 20480 + (B) * 2560 + br); \
      bf16x8 bl = *(const bf16x8*)(XS + 25600 + (B) * 2560 + br); \
      accA[eb] = __builtin_amdgcn_mfma_f32_16x16x32_bf16(ah, bh, accA[eb], 0, 0, 0); \
      accB[eb] = __builtin_amdgcn_mfma_f32_16x16x32_bf16(ah, bm, accB[eb], 0, 0, 0); \
      accB[eb] = __builtin_amdgcn_mfma_f32_16x16x32_bf16(am, bh, accB[eb], 0, 0, 0); \
      accB[eb] = __builtin_amdgcn_mfma_f32_16x16x32_bf16(am, bm, accB[eb], 0, 0, 0); \
      accB[eb] = __builtin_amdgcn_mfma_f32_16x16x32_bf16(ah, bl, accB[eb], 0, 0, 0); \
      accB[eb] = __builtin_amdgcn_mfma_f32_16x16x32_bf16(al, bh, accB[eb], 0, 0, 0); \
    } }

  LOADCH(0);
  WRITECH(0);
  __syncthreads();
#pragma unroll 1
  for (int t = 0; t < 32; t++) {
    if (t < 31) LOADCH((t + 1) * 32);
    COMPUTECH(t & 1);
    if ((t & 7) == 7) {
#pragma unroll
      for (int eb = 0; eb < 4; eb++) {
#pragma unroll
        for (int r = 0; r < 4; r++)
          accD[eb][r] += (double)accA[eb][r] + (double)accB[eb][r];
        accA[eb] = (f32x4)0.f; accB[eb] = (f32x4)0.f;
      }
    }
    if (t < 31) WRITECH((t + 1) & 1);
    __syncthreads();
  }

  double* outp = Lpart + (size_t)ks * NT * NE;
#pragma unroll
  for (int eb = 0; eb < 4; eb++)
#pragma unroll
    for (int r = 0; r < 4; r++) {
      int trow = w * 16 + l4 * 4 + r;
      outp[(size_t)(row0 + trow) * NE + eb * 16 + l15] = accD[eb][r];
    }
}

// ---------------- K2: reduce partials + center + softmax1 + gram ------------
__launch_bounds__(256)
__global__ void k_post(const double* __restrict__ Lpart, const float* __restrict__ b,
                       float* __restrict__ Lbuf, u64* __restrict__ CmAcc) {
  __shared__ float ms[64 * 68];
  const int tid = threadIdx.x, bid = blockIdx.x;
  const int tg = tid >> 2, q = tid & 3;
  const int row = bid * 64 + tg;
  float l[16], m[16];
  {
    const double* p0 = Lpart + (size_t)row * NE + q * 16;
    const double* p1 = p0 + (size_t)NT * NE;
#pragma unroll
    for (int i = 0; i < 4; i++) {
      float4 bv = *(const float4*)(b + q * 16 + i * 4);
      l[i * 4 + 0] = (float)(p0[i * 4 + 0] + p1[i * 4 + 0]) + bv.x;
      l[i * 4 + 1] = (float)(p0[i * 4 + 1] + p1[i * 4 + 1]) + bv.y;
      l[i * 4 + 2] = (float)(p0[i * 4 + 2] + p1[i * 4 + 2]) + bv.z;
      l[i * 4 + 3] = (float)(p0[i * 4 + 3] + p1[i * 4 + 3]) + bv.w;
    }
    float s = 0.f;
#pragma unroll
    for (int j = 0; j < 16; j++) s += l[j];
    s = warp4_sum(s);
    const float mean = s * (1.0f / 64.0f);
    float mx = -1e30f;
#pragma unroll
    for (int j = 0; j < 16; j++) { l[j] -= mean; mx = fmaxf(mx, l[j]); }
    mx = warp4_max(mx);
#pragma unroll
    for (int i = 0; i < 4; i++)
      *(float4*)(Lbuf + (size_t)row * NE + q * 16 + i * 4) =
          make_float4(l[i * 4], l[i * 4 + 1], l[i * 4 + 2], l[i * 4 + 3]);
    float ps = 0.f;
#pragma unroll
    for (int j = 0; j < 16; j++) { m[j] = expf(l[j] - mx); ps += m[j]; }
    ps = warp4_sum(ps);
    const float inv = 1.0f / ps;
#pragma unroll
    for (int j = 0; j < 16; j++) m[j] *= inv;
#pragma unroll
    for (int i = 0; i < 4; i++)
      *(float4*)(ms + tg * 68 + q * 16 + i * 4) =
          make_float4(m[i * 4], m[i * 4 + 1], m[i * 4 + 2], m[i * 4 + 3]);
  }
  __syncthreads();
  // gram partial -> slotted fx atomics (slot = bid & 3)
  const int gi0 = (tid >> 4) * 4;
  const int gj0 = (tid & 15) * 4;
  float ga[4][4];
#pragma unroll
  for (int a = 0; a < 4; a++)
#pragma unroll
    for (int c = 0; c < 4; c++) ga[a][c] = 0.f;
  for (int t = 0; t < 64; t++) {
    float4 a = *(const float4*)(ms + t * 68 + gi0);
    float4 bb = *(const float4*)(ms + t * 68 + gj0);
    ga[0][0] = fmaf(a.x, bb.x, ga[0][0]); ga[0][1] = fmaf(a.x, bb.y, ga[0][1]);
    ga[0][2] = fmaf(a.x, bb.z, ga[0][2]); ga[0][3] = fmaf(a.x, bb.w, ga[0][3]);
    ga[1][0] = fmaf(a.y, bb.x, ga[1][0]); ga[1][1] = fmaf(a.y, bb.y, ga[1][1]);
    ga[1][2] = fmaf(a.y, bb.z, ga[1][2]); ga[1][3] = fmaf(a.y, bb.w, ga[1][3]);
    ga[2][0] = fmaf(a.z, bb.x, ga[2][0]); ga[2][1] = fmaf(a.z, bb.y, ga[2][1]);
    ga[2][2] = fmaf(a.z, bb.z, ga[2][2]); ga[2][3] = fmaf(a.z, bb.w, ga[2][3]);
    ga[3][0] = fmaf(a.w, bb.x, ga[3][0]); ga[3][1] = fmaf(a.w, bb.y, ga[3][1]);
    ga[3][2] = fmaf(a.w, bb.z, ga[3][2]); ga[3][3] = fmaf(a.w, bb.w, ga[3][3]);
  }
  u64* slot = CmAcc + (size_t)(bid & 3) * 4096;
#pragma unroll
  for (int ii = 0; ii < 4; ii++)
#pragma unroll
    for (int jj = 0; jj < 4; jj++)
      atomicAdd(slot + (gi0 + ii) * 64 + gj0 + jj, to_fx(ga[ii][jj]));
}

// ---------------- K3: correction + softmax2 -> M0; emit P0 ------------------
__launch_bounds__(256)
__global__ void k_correct(const float* __restrict__ Lbuf, const u64* __restrict__ CmAcc,
                          float* __restrict__ M0, u64* __restrict__ p0Acc) {
  __shared__ float ms[64 * 68];
  __shared__ float Cs[4096];
  __shared__ float cred[256];
  const int tid = threadIdx.x, bid = blockIdx.x;
  const int tg = tid >> 2, q = tid & 3;
  const int lane = tid & 63, w = tid >> 6;
  const int row = bid * 64 + tg;
  float l[16], m[16];
#pragma unroll
  for (int i = 0; i < 4; i++) {
    float4 lv = *(const float4*)(Lbuf + (size_t)row * NE + q * 16 + i * 4);
    l[i * 4 + 0] = lv.x; l[i * 4 + 1] = lv.y; l[i * 4 + 2] = lv.z; l[i * 4 + 3] = lv.w;
  }
  // recompute softmax1 (bit-identical to k_post: same op order on same values)
  {
    float mx = -1e30f;
#pragma unroll
    for (int j = 0; j < 16; j++) mx = fmaxf(mx, l[j]);
    mx = warp4_max(mx);
    float ps = 0.f;
#pragma unroll
    for (int j = 0; j < 16; j++) { m[j] = expf(l[j] - mx); ps += m[j]; }
    ps = warp4_sum(ps);
    const float inv = 1.0f / ps;
#pragma unroll
    for (int j = 0; j < 16; j++) m[j] *= inv;
#pragma unroll
    for (int i = 0; i < 4; i++)
      *(float4*)(ms + tg * 68 + q * 16 + i * 4) =
          make_float4(m[i * 4], m[i * 4 + 1], m[i * 4 + 2], m[i * 4 + 3]);
  }
  // C from 4 slots, zero diag
#pragma unroll 4
  for (int i = 0; i < 16; i++) {
    int idx = tid + i * 256;
    u64 s = CmAcc[idx] + CmAcc[4096 + idx] + CmAcc[8192 + idx] + CmAcc[12288 + idx];
    float v = (float)((double)s * (1.0 / 4294967296.0));
    int r = idx >> 6, c = idx & 63;
    Cs[idx] = (r == c) ? 0.f : v;
  }
  __syncthreads();
  // correction + softmax2
  {
    float g[16];
#pragma unroll
    for (int j = 0; j < 16; j++) g[j] = 0.f;
    for (int f = 0; f < 64; f++) {
      float mf = ms[tg * 68 + f];
#pragma unroll
      for (int i = 0; i < 4; i++) {
        float4 cv = *(const float4*)(Cs + f * 64 + q * 16 + i * 4);
        g[i * 4 + 0] = fmaf(mf, cv.x, g[i * 4 + 0]);
        g[i * 4 + 1] = fmaf(mf, cv.y, g[i * 4 + 1]);
        g[i * 4 + 2] = fmaf(mf, cv.z, g[i * 4 + 2]);
        g[i * 4 + 3] = fmaf(mf, cv.w, g[i * 4 + 3]);
      }
    }
    float dot = 0.f;
#pragma unroll
    for (int j = 0; j < 16; j++) { g[j] *= 4.f; dot += m[j] * g[j]; }
    dot = warp4_sum(dot);
    float mx = -1e30f;
#pragma unroll
    for (int j = 0; j < 16; j++) {
      l[j] = l[j] - LTAX * (m[j] * (g[j] - dot));
      mx = fmaxf(mx, l[j]);
    }
    mx = warp4_max(mx);
    float ps = 0.f;
#pragma unroll
    for (int j = 0; j < 16; j++) { m[j] = expf(l[j] - mx); ps += m[j]; }
    ps = warp4_sum(ps);
    const float inv = 1.0f / ps;
#pragma unroll
    for (int j = 0; j < 16; j++) m[j] *= inv;
#pragma unroll
    for (int i = 0; i < 4; i++)
      *(float4*)(M0 + (size_t)row * NE + q * 16 + i * 4) =
          make_float4(m[i * 4], m[i * 4 + 1], m[i * 4 + 2], m[i * 4 + 3]);
  }
  // P0 partial = colsum of M0 over this block's 64 tokens
  {
    float cs[16];
#pragma unroll
    for (int j = 0; j < 16; j++) cs[j] = m[j];
#pragma unroll
    for (int j = 0; j < 16; j++) {
      cs[j] += __shfl_xor(cs[j], 4);  cs[j] += __shfl_xor(cs[j], 8);
      cs[j] += __shfl_xor(cs[j], 16); cs[j] += __shfl_xor(cs[j], 32);
    }
    if ((lane >> 2) == 0) {
#pragma unroll
      for (int j = 0; j < 16; j++) cred[w * 64 + lane * 16 + j] = cs[j];
    }
    __syncthreads();
    if (tid < 64)
      atomicAdd(p0Acc + (size_t)(bid & 15) * 64 + tid,
                to_fx(cred[tid] + cred[64 + tid] + cred[128 + tid] + cred[192 + tid]));
  }
}

// ---------------- K4: one factored Sinkhorn iteration -----------------------
// V(e) = 2^8 / P_prev(e)  (exact 2^k scalings cancel; clips never bind),
// Q(t) = sum_e M0(t,e) V(e), U(t)=1/Q(t), P_out(e) = sum_t U(t) M0(t,e).
__launch_bounds__(256)
__global__ void k_sink(const float* __restrict__ M0, const u64* __restrict__ pin,
                       u64* __restrict__ pout) {
  __shared__ float fac[64];
  __shared__ float cred[256];
  const int tid = threadIdx.x, bid = blockIdx.x;
  const int tg = tid >> 2, q = tid & 3;
  const int lane = tid & 63, w = tid >> 6;
  const int row = bid * 64 + tg;
  if (tid < 64) {
    u64 s = 0;
#pragma unroll
    for (int sl = 0; sl < 16; sl++) s += pin[sl * 64 + tid];
    float P = (float)((double)s * (1.0 / 4294967296.0));
    fac[tid] = 256.0f / fmaxf(P, 1e-30f);     // V(e)
  }
  __syncthreads();
  float mv[16];
#pragma unroll
  for (int i = 0; i < 4; i++) {
    float4 v = *(const float4*)(M0 + (size_t)row * NE + q * 16 + i * 4);
    mv[i * 4 + 0] = v.x; mv[i * 4 + 1] = v.y; mv[i * 4 + 2] = v.z; mv[i * 4 + 3] = v.w;
  }
  float Q = 0.f;
#pragma unroll
  for (int j = 0; j < 16; j++) Q = fmaf(mv[j], fac[q * 16 + j], Q);
  Q = warp4_sum(Q);
  const float U = 1.0f / fmaxf(Q, 1e-30f);
  float cs[16];
#pragma unroll
  for (int j = 0; j < 16; j++) cs[j] = U * mv[j];
#pragma unroll
  for (int j = 0; j < 16; j++) {
    cs[j] += __shfl_xor(cs[j], 4);  cs[j] += __shfl_xor(cs[j], 8);
    cs[j] += __shfl_xor(cs[j], 16); cs[j] += __shfl_xor(cs[j], 32);
  }
  if ((lane >> 2) == 0) {
#pragma unroll
    for (int j = 0; j < 16; j++) cred[w * 64 + lane * 16 + j] = cs[j];
  }
  __syncthreads();
  if (tid < 64)
    atomicAdd(pout + (size_t)(bid & 15) * 64 + tid,
              to_fx(cred[tid] + cred[64 + tid] + cred[128 + tid] + cred[192 + tid]));
}

// ---------------- K5: final M10 + damping + hysteresis + topk ---------------
__launch_bounds__(256)
__global__ void k_final(const float* __restrict__ M0, const u64* __restrict__ pin,
                        const float* __restrict__ pp, const void* __restrict__ pmask,
                        float* __restrict__ out) {
  __shared__ float fac[64];
  __shared__ int s_cnt[256];
  __shared__ int s_flag;
  const int tid = threadIdx.x, bid = blockIdx.x;
  const int tg = tid >> 2, q = tid & 3;
  const int lane = tid & 63;
  const int row = bid * 64 + tg;

  // prev_mask format detect (first 4096 bytes): u8->512, f32->256, i32->128
  {
    uint4 v = ((const uint4*)pmask)[tid];
    int c = 0; u32 ww;
    ww = v.x; c += ((ww & 0xffu) != 0) + ((ww & 0xff00u) != 0) + ((ww & 0xff0000u) != 0) + ((ww & 0xff000000u) != 0);
    ww = v.y; c += ((ww & 0xffu) != 0) + ((ww & 0xff00u) != 0) + ((ww & 0xff0000u) != 0) + ((ww & 0xff000000u) != 0);
    ww = v.z; c += ((ww & 0xffu) != 0) + ((ww & 0xff00u) != 0) + ((ww & 0xff0000u) != 0) + ((ww & 0xff000000u) != 0);
    ww = v.w; c += ((ww & 0xffu) != 0) + ((ww & 0xff00u) != 0) + ((ww & 0xff0000u) != 0) + ((ww & 0xff000000u) != 0);
    s_cnt[tid] = c;
    __syncthreads();
    for (int s = 128; s; s >>= 1) { if (tid < s) s_cnt[tid] += s_cnt[tid + s]; __syncthreads(); }
    if (tid == 0) { int n = s_cnt[0]; s_flag = (n > 384) ? 0 : ((n > 192) ? 2 : 1); }
  }
  if (tid < 64) {
    u64 s = 0;
#pragma unroll
    for (int sl = 0; sl < 16; sl++) s += pin[sl * 64 + tid];
    float P = (float)((double)s * (1.0 / 4294967296.0));
    fac[tid] = 256.0f / fmaxf(P, 1e-30f);     // V10
  }
  __syncthreads();

  float mv[16];
#pragma unroll
  for (int i = 0; i < 4; i++) {
    float4 v = *(const float4*)(M0 + (size_t)row * NE + q * 16 + i * 4);
    mv[i * 4 + 0] = v.x; mv[i * 4 + 1] = v.y; mv[i * 4 + 2] = v.z; mv[i * 4 + 3] = v.w;
  }
  float Q = 0.f;
#pragma unroll
  for (int j = 0; j < 16; j++) Q = fmaf(mv[j], fac[q * 16 + j], Q);
  Q = warp4_sum(Q);
  const float U = 1.0f / fmaxf(Q, 1e-30f);
  float m[16];
#pragma unroll
  for (int j = 0; j < 16; j++) m[j] = U * mv[j] * fac[q * 16 + j];   // M10 row

  const int flag = s_flag;
  float pv[16], mk[16];
#pragma unroll
  for (int i = 0; i < 4; i++) {
    float4 v = *(const float4*)(pp + (size_t)row * NE + q * 16 + i * 4);
    pv[i * 4 + 0] = v.x; pv[i * 4 + 1] = v.y; pv[i * 4 + 2] = v.z; pv[i * 4 + 3] = v.w;
  }
  if (flag == 0) {
    const u32* pb = (const u32*)pmask + row * 16 + q * 4;
#pragma unroll
    for (int i = 0; i < 4; i++) {
      u32 ww = pb[i];
      mk[i * 4 + 0] = (ww & 0xffu) ? 1.f : 0.f;
      mk[i * 4 + 1] = (ww & 0xff00u) ? 1.f : 0.f;
      mk[i * 4 + 2] = (ww & 0xff0000u) ? 1.f : 0.f;
      mk[i * 4 + 3] = (ww & 0xff000000u) ? 1.f : 0.f;
    }
  } else if (flag == 1) {
    const int* pb = (const int*)pmask + (size_t)row * NE + q * 16;
#pragma unroll
    for (int j = 0; j < 16; j++) mk[j] = pb[j] ? 1.f : 0.f;
  } else {
    const float* pb = (const float*)pmask + (size_t)row * NE + q * 16;
#pragma unroll
    for (int j = 0; j < 16; j++) mk[j] = (pb[j] != 0.f) ? 1.f : 0.f;
  }
  float msum = 0.f;
#pragma unroll
  for (int j = 0; j < 16; j++) msum += mk[j];
  msum = warp4_sum(msum);
  const float hscale = HYST / fmaxf(msum, 1.0f);
  float v[16];
  float s = 0.f;
#pragma unroll
  for (int j = 0; j < 16; j++) {
    float base = (1.f - ALPHA) * pv[j] + ALPHA * m[j];
    v[j] = (1.f - HYST) * base + hscale * mk[j];
    s += v[j];
  }
  s = warp4_sum(s);
  const float inv = 1.0f / fmaxf(s, 1e-12f);
#pragma unroll
  for (int j = 0; j < 16; j++) v[j] *= inv;

  float* mout = out;
  float* kout = out + (size_t)NT * NE;
#pragma unroll
  for (int i = 0; i < 4; i++)
    *(float4*)(mout + (size_t)row * NE + q * 16 + i * 4) =
        make_float4(v[i * 4], v[i * 4 + 1], v[i * 4 + 2], v[i * 4 + 3]);

  int cnt[16];
#pragma unroll
  for (int j = 0; j < 16; j++) cnt[j] = 0;
  const int base = lane & ~3;
#pragma unroll
  for (int oq = 0; oq < 4; oq++) {
#pragma unroll
    for (int j2 = 0; j2 < 16; j2++) {
      float ov = __shfl(v[j2], base + oq, 64);
      int oe = oq * 16 + j2;
#pragma unroll
      for (int j = 0; j < 16; j++) {
        int me = q * 16 + j;
        if (ov > v[j] || (ov == v[j] && oe < me)) cnt[j]++;
      }
    }
  }
#pragma unroll
  for (int i = 0; i < 4; i++)
    *(float4*)(kout + (size_t)row * NE + q * 16 + i * 4) =
        make_float4(cnt[i * 4] < TOPK ? 1.f : 0.f, cnt[i * 4 + 1] < TOPK ? 1.f : 0.f,
                    cnt[i * 4 + 2] < TOPK ? 1.f : 0.f, cnt[i * 4 + 3] < TOPK ? 1.f : 0.f);
}

extern "C" void kernel_launch(void* const* d_in, const int* in_sizes, int n_in,
                              void* d_out, int out_size, void* d_ws, size_t ws_size,
                              hipStream_t stream) {
  const float* x = (const float*)d_in[0];
  const float* W = (const float*)d_in[1];
  const float* b = (const float*)d_in[2];
  const float* pp = (const float*)d_in[3];
  const void* pmask = d_in[4];
  float* out = (float*)d_out;

  unsigned char* wsb = (unsigned char*)d_ws;
  u16* Wh = (u16*)(wsb);                          // 256 KB
  u16* Wm = (u16*)(wsb + 262144);                 // 256 KB
  u16* Wl = (u16*)(wsb + 524288);                 // 256 KB
  double* Lpart = (double*)(wsb + 786432);        // 16 MB -> 17563648
  float* Lbuf = (float*)(wsb + 17563648);         // 4 MB  -> 21757952
  float* M0buf = (float*)(wsb + 21757952);        // 4 MB  -> 25952256
  u64* CmAcc = (u64*)(wsb + 25952256);            // 4 slots * 4096 u64 = 128 KB
  u64* pAcc = (u64*)(wsb + 26083328);             // 10 * 16 * 64 u64 = 80 KB

  hipMemsetAsync(wsb + 25952256, 0, 212992, stream);
  k_wsplit3<<<128, 256, 0, stream>>>(W, Wh, Wm, Wl);
  k_gemm<<<512, 256, 0, stream>>>(x, Wh, Wm, Wl, Lpart);
  k_post<<<256, 256, 0, stream>>>(Lpart, b, Lbuf, CmAcc);
  k_correct<<<256, 256, 0, stream>>>(Lbuf, CmAcc, M0buf, pAcc);
  for (int k = 1; k <= 9; k++)
    k_sink<<<256, 256, 0, stream>>>(M0buf, pAcc + (size_t)(k - 1) * 1024,
                                    pAcc + (size_t)k * 1024);
  k_final<<<256, 256, 0, stream>>>(M0buf, pAcc + (size_t)9 * 1024, pp, pmask, out);
}

// Round 12
// 179.749 us; speedup vs baseline: 4.7181x; 1.0087x over previous
//
#include <hip/hip_runtime.h>
#include <math.h>

#define NT 16384
#define DM 2048
#define NE 64
#define TOPK 8
#define LTAX 0.04f
#define HYST 0.1f
#define ALPHA 0.7f

typedef unsigned int u32;
typedef unsigned short u16;
typedef unsigned long long u64;
typedef __attribute__((ext_vector_type(8))) short bf16x8;
typedef __attribute__((ext_vector_type(4))) float f32x4;

__device__ __forceinline__ float warp4_sum(float v) {
  v += __shfl_xor(v, 1); v += __shfl_xor(v, 2); return v;
}
__device__ __forceinline__ float warp4_max(float v) {
  v = fmaxf(v, __shfl_xor(v, 1)); v = fmaxf(v, __shfl_xor(v, 2)); return v;
}
__device__ __forceinline__ u16 f2bf(float f) {   // RNE f32->bf16
  u32 u = __float_as_uint(f);
  return (u16)((u + 0x7fffu + ((u >> 16) & 1u)) >> 16);
}
__device__ __forceinline__ float bf2f(u16 h) { return __uint_as_float(((u32)h) << 16); }

__device__ __forceinline__ void split3(float a, short& h, short& m, short& l) {
  u16 hh = f2bf(a);  float r1 = a - bf2f(hh);     // exact (Sterbenz)
  u16 mm = f2bf(r1); float r2 = r1 - bf2f(mm);    // exact
  h = (short)hh; m = (short)mm; l = (short)f2bf(r2);
}

// fixed-point 2^32: exact-commutative integer atomics => deterministic
__device__ __forceinline__ u64 to_fx(float v) {
  return (u64)__double2ll_rn((double)v * 4294967296.0);
}

// ---------------- K-1: fast zero of accumulator region ----------------------
__global__ void k_zero(u64* __restrict__ p, int n) {
  int i = blockIdx.x * 256 + threadIdx.x;
  if (i < n) p[i] = 0ull;
}

// ---------------- K0: W -> bf16 hi/mid/lo ----------------------------------
__global__ void k_wsplit3(const float* __restrict__ W, u16* __restrict__ Wh,
                          u16* __restrict__ Wm, u16* __restrict__ Wl) {
  int idx = (blockIdx.x * 256 + threadIdx.x) * 4;
  float4 v = *(const float4*)(W + idx);
  short h[4], m[4], l[4];
  split3(v.x, h[0], m[0], l[0]);
  split3(v.y, h[1], m[1], l[1]);
  split3(v.z, h[2], m[2], l[2]);
  split3(v.w, h[3], m[3], l[3]);
  *(ushort4*)(Wh + idx) = make_ushort4((u16)h[0], (u16)h[1], (u16)h[2], (u16)h[3]);
  *(ushort4*)(Wm + idx) = make_ushort4((u16)m[0], (u16)m[1], (u16)m[2], (u16)m[3]);
  *(ushort4*)(Wl + idx) = make_ushort4((u16)l[0], (u16)l[1], (u16)l[2], (u16)l[3]);
}

// ---------------- K1: MFMA GEMM, split-K=2, f64 partials (proven) -----------
__launch_bounds__(256, 2)
__global__ void k_gemm(const float* __restrict__ x, const u16* __restrict__ Whg,
                       const u16* __restrict__ Wmg, const u16* __restrict__ Wlg,
                       double* __restrict__ Lpart) {
  __shared__ __align__(16) u16 XS[30720];   // 6 arrays x 2 buf x [64][40]
  const int tid = threadIdx.x;
  const int bid = blockIdx.x;
  const int tile = bid >> 1, ks = bid & 1;
  const int row0 = tile * 64;
  const int k0 = ks * 1024;
  const int lane = tid & 63, w = tid >> 6, l15 = lane & 15, l4 = lane >> 4;
  const int srow = tid >> 2, c8 = (tid & 3) * 8;
  const int stoff = srow * 40 + c8;

  f32x4 accA[4], accB[4];
  double accD[4][4];
#pragma unroll
  for (int eb = 0; eb < 4; eb++) {
    accA[eb] = (f32x4)0.f; accB[eb] = (f32x4)0.f;
#pragma unroll
    for (int r = 0; r < 4; r++) accD[eb][r] = 0.0;
  }

  float4 xq0, xq1;
  uint4 whv, wmv, wlv;
  const float* xrowp = x + (size_t)(row0 + srow) * DM + k0 + c8;
  const u16* whp = Whg + srow * DM + k0 + c8;
  const u16* wmp = Wmg + srow * DM + k0 + c8;
  const u16* wlp = Wlg + srow * DM + k0 + c8;

#define LOADCH(KC) { \
    xq0 = *(const float4*)(xrowp + (KC)); \
    xq1 = *(const float4*)(xrowp + (KC) + 4); \
    whv = *(const uint4*)(whp + (KC)); \
    wmv = *(const uint4*)(wmp + (KC)); \
    wlv = *(const uint4*)(wlp + (KC)); }

#define WRITECH(B) { \
    short ha[8], ma[8], la[8]; \
    split3(xq0.x, ha[0], ma[0], la[0]); \
    split3(xq0.y, ha[1], ma[1], la[1]); \
    split3(xq0.z, ha[2], ma[2], la[2]); \
    split3(xq0.w, ha[3], ma[3], la[3]); \
    split3(xq1.x, ha[4], ma[4], la[4]); \
    split3(xq1.y, ha[5], ma[5], la[5]); \
    split3(xq1.z, ha[6], ma[6], la[6]); \
    split3(xq1.w, ha[7], ma[7], la[7]); \
    bf16x8 xh8, xm8, xl8; \
    _Pragma("unroll") \
    for (int z = 0; z < 8; z++) { xh8[z] = ha[z]; xm8[z] = ma[z]; xl8[z] = la[z]; } \
    *(bf16x8*)(XS + 0     + (B) * 2560 + stoff) = xh8; \
    *(bf16x8*)(XS + 5120  + (B) * 2560 + stoff) = xm8; \
    *(bf16x8*)(XS + 10240 + (B) * 2560 + stoff) = xl8; \
    *(uint4*)(XS + 15360 + (B) * 2560 + stoff) = whv; \
    *(uint4*)(XS + 20480 + (B) * 2560 + stoff) = wmv; \
    *(uint4*)(XS + 25600 + (B) * 2560 + stoff) = wlv; }

#define COMPUTECH(B) { \
    const int ar = (w * 16 + l15) * 40 + l4 * 8; \
    bf16x8 ah = *(const bf16x8*)(XS + 0     + (B) * 2560 + ar); \
    bf16x8 am = *(const bf16x8*)(XS + 5120  + (B) * 2560 + ar); \
    bf16x8 al = *(const bf16x8*)(XS + 10240 + (B) * 2560 + ar); \
    _Pragma("unroll") \
    for (int eb = 0; eb < 4; eb++) { \
      const int br = (eb * 16 + l15) * 40 + l4 * 8; \
      bf16x8 bh = *(const bf16x8*)(XS + 15360 + (B) * 2560 + br); \
      bf16x8 bm = *(const bf16x8*)(XS + 20480 + (B) * 2560 + br); \
      bf16x8 bl = *(const bf16x8*)(XS + 25600 + (B) * 2560 + br); \
      accA[eb] = __builtin_amdgcn_mfma_f32_16x16x32_bf16(ah, bh, accA[eb], 0, 0, 0); \
      accB[eb] = __builtin_amdgcn_mfma_f32_16x16x32_bf16(ah, bm, accB[eb], 0, 0, 0); \
      accB[eb] = __builtin_amdgcn_mfma_f32_16x16x32_bf16(am, bh, accB[eb], 0, 0, 0); \
      accB[eb] = __builtin_amdgcn_mfma_f32_16x16x32_bf16(am, bm, accB[eb], 0, 0, 0); \
      accB[eb] = __builtin_amdgcn_mfma_f32_16x16x32_bf16(ah, bl, accB[eb], 0, 0, 0); \
      accB[eb] = __builtin_amdgcn_mfma_f32_16x16x32_bf16(al, bh, accB[eb], 0, 0, 0); \
    } }

  LOADCH(0);
  WRITECH(0);
  __syncthreads();
#pragma unroll 1
  for (int t = 0; t < 32; t++) {
    if (t < 31) LOADCH((t + 1) * 32);
    COMPUTECH(t & 1);
    if ((t & 7) == 7) {
#pragma unroll
      for (int eb = 0; eb < 4; eb++) {
#pragma unroll
        for (int r = 0; r < 4; r++)
          accD[eb][r] += (double)accA[eb][r] + (double)accB[eb][r];
        accA[eb] = (f32x4)0.f; accB[eb] = (f32x4)0.f;
      }
    }
    if (t < 31) WRITECH((t + 1) & 1);
    __syncthreads();
  }

  double* outp = Lpart + (size_t)ks * NT * NE;
#pragma unroll
  for (int eb = 0; eb < 4; eb++)
#pragma unroll
    for (int r = 0; r < 4; r++) {
      int trow = w * 16 + l4 * 4 + r;
      outp[(size_t)(row0 + trow) * NE + eb * 16 + l15] = accD[eb][r];
    }
}

// ---------------- K2: reduce partials + center + softmax1 + gram ------------
__launch_bounds__(256)
__global__ void k_post(const double* __restrict__ Lpart, const float* __restrict__ b,
                       float* __restrict__ Lbuf, u64* __restrict__ CmAcc) {
  __shared__ float ms[64 * 68];
  const int tid = threadIdx.x, bid = blockIdx.x;
  const int tg = tid >> 2, q = tid & 3;
  const int row = bid * 64 + tg;
  float l[16], m[16];
  {
    const double* p0 = Lpart + (size_t)row * NE + q * 16;
    const double* p1 = p0 + (size_t)NT * NE;
#pragma unroll
    for (int i = 0; i < 4; i++) {
      float4 bv = *(const float4*)(b + q * 16 + i * 4);
      l[i * 4 + 0] = (float)(p0[i * 4 + 0] + p1[i * 4 + 0]) + bv.x;
      l[i * 4 + 1] = (float)(p0[i * 4 + 1] + p1[i * 4 + 1]) + bv.y;
      l[i * 4 + 2] = (float)(p0[i * 4 + 2] + p1[i * 4 + 2]) + bv.z;
      l[i * 4 + 3] = (float)(p0[i * 4 + 3] + p1[i * 4 + 3]) + bv.w;
    }
    float s = 0.f;
#pragma unroll
    for (int j = 0; j < 16; j++) s += l[j];
    s = warp4_sum(s);
    const float mean = s * (1.0f / 64.0f);
    float mx = -1e30f;
#pragma unroll
    for (int j = 0; j < 16; j++) { l[j] -= mean; mx = fmaxf(mx, l[j]); }
    mx = warp4_max(mx);
#pragma unroll
    for (int i = 0; i < 4; i++)
      *(float4*)(Lbuf + (size_t)row * NE + q * 16 + i * 4) =
          make_float4(l[i * 4], l[i * 4 + 1], l[i * 4 + 2], l[i * 4 + 3]);
    float ps = 0.f;
#pragma unroll
    for (int j = 0; j < 16; j++) { m[j] = expf(l[j] - mx); ps += m[j]; }
    ps = warp4_sum(ps);
    const float inv = 1.0f / ps;
#pragma unroll
    for (int j = 0; j < 16; j++) m[j] *= inv;
#pragma unroll
    for (int i = 0; i < 4; i++)
      *(float4*)(ms + tg * 68 + q * 16 + i * 4) =
          make_float4(m[i * 4], m[i * 4 + 1], m[i * 4 + 2], m[i * 4 + 3]);
  }
  __syncthreads();
  // gram partial -> slotted fx atomics (slot = bid & 3)
  const int gi0 = (tid >> 4) * 4;
  const int gj0 = (tid & 15) * 4;
  float ga[4][4];
#pragma unroll
  for (int a = 0; a < 4; a++)
#pragma unroll
    for (int c = 0; c < 4; c++) ga[a][c] = 0.f;
  for (int t = 0; t < 64; t++) {
    float4 a = *(const float4*)(ms + t * 68 + gi0);
    float4 bb = *(const float4*)(ms + t * 68 + gj0);
    ga[0][0] = fmaf(a.x, bb.x, ga[0][0]); ga[0][1] = fmaf(a.x, bb.y, ga[0][1]);
    ga[0][2] = fmaf(a.x, bb.z, ga[0][2]); ga[0][3] = fmaf(a.x, bb.w, ga[0][3]);
    ga[1][0] = fmaf(a.y, bb.x, ga[1][0]); ga[1][1] = fmaf(a.y, bb.y, ga[1][1]);
    ga[1][2] = fmaf(a.y, bb.z, ga[1][2]); ga[1][3] = fmaf(a.y, bb.w, ga[1][3]);
    ga[2][0] = fmaf(a.z, bb.x, ga[2][0]); ga[2][1] = fmaf(a.z, bb.y, ga[2][1]);
    ga[2][2] = fmaf(a.z, bb.z, ga[2][2]); ga[2][3] = fmaf(a.z, bb.w, ga[2][3]);
    ga[3][0] = fmaf(a.w, bb.x, ga[3][0]); ga[3][1] = fmaf(a.w, bb.y, ga[3][1]);
    ga[3][2] = fmaf(a.w, bb.z, ga[3][2]); ga[3][3] = fmaf(a.w, bb.w, ga[3][3]);
  }
  u64* slot = CmAcc + (size_t)(bid & 3) * 4096;
#pragma unroll
  for (int ii = 0; ii < 4; ii++)
#pragma unroll
    for (int jj = 0; jj < 4; jj++)
      atomicAdd(slot + (gi0 + ii) * 64 + gj0 + jj, to_fx(ga[ii][jj]));
}

// ---------------- K3: correction + softmax2 -> M0; emit P0 ------------------
__launch_bounds__(256)
__global__ void k_correct(const float* __restrict__ Lbuf, const u64* __restrict__ CmAcc,
                          float* __restrict__ M0, u64* __restrict__ p0Acc) {
  __shared__ float ms[64 * 68];
  __shared__ float Cs[4096];
  __shared__ float cred[256];
  const int tid = threadIdx.x, bid = blockIdx.x;
  const int tg = tid >> 2, q = tid & 3;
  const int lane = tid & 63, w = tid >> 6;
  const int row = bid * 64 + tg;
  float l[16], m[16];
#pragma unroll
  for (int i = 0; i < 4; i++) {
    float4 lv = *(const float4*)(Lbuf + (size_t)row * NE + q * 16 + i * 4);
    l[i * 4 + 0] = lv.x; l[i * 4 + 1] = lv.y; l[i * 4 + 2] = lv.z; l[i * 4 + 3] = lv.w;
  }
  // recompute softmax1 (bit-identical op order on identical values)
  {
    float mx = -1e30f;
#pragma unroll
    for (int j = 0; j < 16; j++) mx = fmaxf(mx, l[j]);
    mx = warp4_max(mx);
    float ps = 0.f;
#pragma unroll
    for (int j = 0; j < 16; j++) { m[j] = expf(l[j] - mx); ps += m[j]; }
    ps = warp4_sum(ps);
    const float inv = 1.0f / ps;
#pragma unroll
    for (int j = 0; j < 16; j++) m[j] *= inv;
#pragma unroll
    for (int i = 0; i < 4; i++)
      *(float4*)(ms + tg * 68 + q * 16 + i * 4) =
          make_float4(m[i * 4], m[i * 4 + 1], m[i * 4 + 2], m[i * 4 + 3]);
  }
  // C from 4 slots, zero diag
#pragma unroll 4
  for (int i = 0; i < 16; i++) {
    int idx = tid + i * 256;
    u64 s = CmAcc[idx] + CmAcc[4096 + idx] + CmAcc[8192 + idx] + CmAcc[12288 + idx];
    float v = (float)((double)s * (1.0 / 4294967296.0));
    int r = idx >> 6, c = idx & 63;
    Cs[idx] = (r == c) ? 0.f : v;
  }
  __syncthreads();
  // correction + softmax2
  {
    float g[16];
#pragma unroll
    for (int j = 0; j < 16; j++) g[j] = 0.f;
    for (int f = 0; f < 64; f++) {
      float mf = ms[tg * 68 + f];
#pragma unroll
      for (int i = 0; i < 4; i++) {
        float4 cv = *(const float4*)(Cs + f * 64 + q * 16 + i * 4);
        g[i * 4 + 0] = fmaf(mf, cv.x, g[i * 4 + 0]);
        g[i * 4 + 1] = fmaf(mf, cv.y, g[i * 4 + 1]);
        g[i * 4 + 2] = fmaf(mf, cv.z, g[i * 4 + 2]);
        g[i * 4 + 3] = fmaf(mf, cv.w, g[i * 4 + 3]);
      }
    }
    float dot = 0.f;
#pragma unroll
    for (int j = 0; j < 16; j++) { g[j] *= 4.f; dot += m[j] * g[j]; }
    dot = warp4_sum(dot);
    float mx = -1e30f;
#pragma unroll
    for (int j = 0; j < 16; j++) {
      l[j] = l[j] - LTAX * (m[j] * (g[j] - dot));
      mx = fmaxf(mx, l[j]);
    }
    mx = warp4_max(mx);
    float ps = 0.f;
#pragma unroll
    for (int j = 0; j < 16; j++) { m[j] = expf(l[j] - mx); ps += m[j]; }
    ps = warp4_sum(ps);
    const float inv = 1.0f / ps;
#pragma unroll
    for (int j = 0; j < 16; j++) m[j] *= inv;
#pragma unroll
    for (int i = 0; i < 4; i++)
      *(float4*)(M0 + (size_t)row * NE + q * 16 + i * 4) =
          make_float4(m[i * 4], m[i * 4 + 1], m[i * 4 + 2], m[i * 4 + 3]);
  }
  // P0 partial = colsum of M0 over this block's 64 tokens
  {
    float cs[16];
#pragma unroll
    for (int j = 0; j < 16; j++) cs[j] = m[j];
#pragma unroll
    for (int j = 0; j < 16; j++) {
      cs[j] += __shfl_xor(cs[j], 4);  cs[j] += __shfl_xor(cs[j], 8);
      cs[j] += __shfl_xor(cs[j], 16); cs[j] += __shfl_xor(cs[j], 32);
    }
    if ((lane >> 2) == 0) {
#pragma unroll
      for (int j = 0; j < 16; j++) cred[w * 64 + lane * 16 + j] = cs[j];
    }
    __syncthreads();
    if (tid < 64)
      atomicAdd(p0Acc + (size_t)(bid & 15) * 64 + tid,
                to_fx(cred[tid] + cred[64 + tid] + cred[128 + tid] + cred[192 + tid]));
  }
}

// ---------------- K4: one factored Sinkhorn iteration -----------------------
// V(e) = 2^8 / P_prev(e); Q(t) = sum_e M0(t,e) V(e); P_out(e) = sum_t M0(t,e)/Q(t)
__launch_bounds__(256)
__global__ void k_sink(const float* __restrict__ M0, const u64* __restrict__ pin,
                       u64* __restrict__ pout) {
  __shared__ float fac[64];
  __shared__ float cred[256];
  const int tid = threadIdx.x, bid = blockIdx.x;
  const int tg = tid >> 2, q = tid & 3;
  const int lane = tid & 63, w = tid >> 6;
  const int row = bid * 64 + tg;
  if (tid < 64) {
    u64 s = 0;
#pragma unroll
    for (int sl = 0; sl < 16; sl++) s += pin[sl * 64 + tid];
    float P = (float)((double)s * (1.0 / 4294967296.0));
    fac[tid] = 256.0f / fmaxf(P, 1e-30f);     // V(e)
  }
  __syncthreads();
  float mv[16];
#pragma unroll
  for (int i = 0; i < 4; i++) {
    float4 v = *(const float4*)(M0 + (size_t)row * NE + q * 16 + i * 4);
    mv[i * 4 + 0] = v.x; mv[i * 4 + 1] = v.y; mv[i * 4 + 2] = v.z; mv[i * 4 + 3] = v.w;
  }
  float Q = 0.f;
#pragma unroll
  for (int j = 0; j < 16; j++) Q = fmaf(mv[j], fac[q * 16 + j], Q);
  Q = warp4_sum(Q);
  const float U = 1.0f / fmaxf(Q, 1e-30f);
  float cs[16];
#pragma unroll
  for (int j = 0; j < 16; j++) cs[j] = U * mv[j];
#pragma unroll
  for (int j = 0; j < 16; j++) {
    cs[j] += __shfl_xor(cs[j], 4);  cs[j] += __shfl_xor(cs[j], 8);
    cs[j] += __shfl_xor(cs[j], 16); cs[j] += __shfl_xor(cs[j], 32);
  }
  if ((lane >> 2) == 0) {
#pragma unroll
    for (int j = 0; j < 16; j++) cred[w * 64 + lane * 16 + j] = cs[j];
  }
  __syncthreads();
  if (tid < 64)
    atomicAdd(pout + (size_t)(bid & 15) * 64 + tid,
              to_fx(cred[tid] + cred[64 + tid] + cred[128 + tid] + cred[192 + tid]));
}

// ---------------- K5: final M10 + damping + hysteresis + topk ---------------
__launch_bounds__(256)
__global__ void k_final(const float* __restrict__ M0, const u64* __restrict__ pin,
                        const float* __restrict__ pp, const void* __restrict__ pmask,
                        float* __restrict__ out) {
  __shared__ float fac[64];
  __shared__ int s_cnt[256];
  __shared__ int s_flag;
  const int tid = threadIdx.x, bid = blockIdx.x;
  const int tg = tid >> 2, q = tid & 3;
  const int lane = tid & 63;
  const int row = bid * 64 + tg;

  // prev_mask format detect (first 4096 bytes): u8->512, f32->256, i32->128
  {
    uint4 v = ((const uint4*)pmask)[tid];
    int c = 0; u32 ww;
    ww = v.x; c += ((ww & 0xffu) != 0) + ((ww & 0xff00u) != 0) + ((ww & 0xff0000u) != 0) + ((ww & 0xff000000u) != 0);
    ww = v.y; c += ((ww & 0xffu) != 0) + ((ww & 0xff00u) != 0) + ((ww & 0xff0000u) != 0) + ((ww & 0xff000000u) != 0);
    ww = v.z; c += ((ww & 0xffu) != 0) + ((ww & 0xff00u) != 0) + ((ww & 0xff0000u) != 0) + ((ww & 0xff000000u) != 0);
    ww = v.w; c += ((ww & 0xffu) != 0) + ((ww & 0xff00u) != 0) + ((ww & 0xff0000u) != 0) + ((ww & 0xff000000u) != 0);
    s_cnt[tid] = c;
    __syncthreads();
    for (int s = 128; s; s >>= 1) { if (tid < s) s_cnt[tid] += s_cnt[tid + s]; __syncthreads(); }
    if (tid == 0) { int n = s_cnt[0]; s_flag = (n > 384) ? 0 : ((n > 192) ? 2 : 1); }
  }
  if (tid < 64) {
    u64 s = 0;
#pragma unroll
    for (int sl = 0; sl < 16; sl++) s += pin[sl * 64 + tid];
    float P = (float)((double)s * (1.0 / 4294967296.0));
    fac[tid] = 256.0f / fmaxf(P, 1e-30f);     // V10
  }
  __syncthreads();

  float mv[16];
#pragma unroll
  for (int i = 0; i < 4; i++) {
    float4 v = *(const float4*)(M0 + (size_t)row * NE + q * 16 + i * 4);
    mv[i * 4 + 0] = v.x; mv[i * 4 + 1] = v.y; mv[i * 4 + 2] = v.z; mv[i * 4 + 3] = v.w;
  }
  float Q = 0.f;
#pragma unroll
  for (int j = 0; j < 16; j++) Q = fmaf(mv[j], fac[q * 16 + j], Q);
  Q = warp4_sum(Q);
  const float U = 1.0f / fmaxf(Q, 1e-30f);
  float m[16];
#pragma unroll
  for (int j = 0; j < 16; j++) m[j] = U * mv[j] * fac[q * 16 + j];   // M10 row

  const int flag = s_flag;
  float pv[16], mk[16];
#pragma unroll
  for (int i = 0; i < 4; i++) {
    float4 v = *(const float4*)(pp + (size_t)row * NE + q * 16 + i * 4);
    pv[i * 4 + 0] = v.x; pv[i * 4 + 1] = v.y; pv[i * 4 + 2] = v.z; pv[i * 4 + 3] = v.w;
  }
  if (flag == 0) {
    const u32* pb = (const u32*)pmask + row * 16 + q * 4;
#pragma unroll
    for (int i = 0; i < 4; i++) {
      u32 ww = pb[i];
      mk[i * 4 + 0] = (ww & 0xffu) ? 1.f : 0.f;
      mk[i * 4 + 1] = (ww & 0xff00u) ? 1.f : 0.f;
      mk[i * 4 + 2] = (ww & 0xff0000u) ? 1.f : 0.f;
      mk[i * 4 + 3] = (ww & 0xff000000u) ? 1.f : 0.f;
    }
  } else if (flag == 1) {
    const int* pb = (const int*)pmask + (size_t)row * NE + q * 16;
#pragma unroll
    for (int j = 0; j < 16; j++) mk[j] = pb[j] ? 1.f : 0.f;
  } else {
    const float* pb = (const float*)pmask + (size_t)row * NE + q * 16;
#pragma unroll
    for (int j = 0; j < 16; j++) mk[j] = (pb[j] != 0.f) ? 1.f : 0.f;
  }
  float msum = 0.f;
#pragma unroll
  for (int j = 0; j < 16; j++) msum += mk[j];
  msum = warp4_sum(msum);
  const float hscale = HYST / fmaxf(msum, 1.0f);
  float v[16];
  float s = 0.f;
#pragma unroll
  for (int j = 0; j < 16; j++) {
    float base = (1.f - ALPHA) * pv[j] + ALPHA * m[j];
    v[j] = (1.f - HYST) * base + hscale * mk[j];
    s += v[j];
  }
  s = warp4_sum(s);
  const float inv = 1.0f / fmaxf(s, 1e-12f);
#pragma unroll
  for (int j = 0; j < 16; j++) v[j] *= inv;

  float* mout = out;
  float* kout = out + (size_t)NT * NE;
#pragma unroll
  for (int i = 0; i < 4; i++)
    *(float4*)(mout + (size_t)row * NE + q * 16 + i * 4) =
        make_float4(v[i * 4], v[i * 4 + 1], v[i * 4 + 2], v[i * 4 + 3]);

  int cnt[16];
#pragma unroll
  for (int j = 0; j < 16; j++) cnt[j] = 0;
  const int base = lane & ~3;
#pragma unroll
  for (int oq = 0; oq < 4; oq++) {
#pragma unroll
    for (int j2 = 0; j2 < 16; j2++) {
      float ov = __shfl(v[j2], base + oq, 64);
      int oe = oq * 16 + j2;
#pragma unroll
      for (int j = 0; j < 16; j++) {
        int me = q * 16 + j;
        if (ov > v[j] || (ov == v[j] && oe < me)) cnt[j]++;
      }
    }
  }
#pragma unroll
  for (int i = 0; i < 4; i++)
    *(float4*)(kout + (size_t)row * NE + q * 16 + i * 4) =
        make_float4(cnt[i * 4] < TOPK ? 1.f : 0.f, cnt[i * 4 + 1] < TOPK ? 1.f : 0.f,
                    cnt[i * 4 + 2] < TOPK ? 1.f : 0.f, cnt[i * 4 + 3] < TOPK ? 1.f : 0.f);
}

extern "C" void kernel_launch(void* const* d_in, const int* in_sizes, int n_in,
                              void* d_out, int out_size, void* d_ws, size_t ws_size,
                              hipStream_t stream) {
  const float* x = (const float*)d_in[0];
  const float* W = (const float*)d_in[1];
  const float* b = (const float*)d_in[2];
  const float* pp = (const float*)d_in[3];
  const void* pmask = d_in[4];
  float* out = (float*)d_out;

  unsigned char* wsb = (unsigned char*)d_ws;
  u16* Wh = (u16*)(wsb);                          // 256 KB
  u16* Wm = (u16*)(wsb + 262144);                 // 256 KB
  u16* Wl = (u16*)(wsb + 524288);                 // 256 KB
  double* Lpart = (double*)(wsb + 786432);        // 16 MB -> 17563648
  float* Lbuf = (float*)(wsb + 17563648);         // 4 MB  -> 21757952
  float* M0buf = (float*)(wsb + 21757952);        // 4 MB  -> 25952256
  u64* CmAcc = (u64*)(wsb + 25952256);            // 4 slots * 4096 u64 = 128 KB
  u64* pAcc = (u64*)(wsb + 26083328);             // 10 * 16 * 64 u64 = 80 KB

  // fast zero of accumulators (26624 u64); hipMemsetAsync's fillBuffer path
  // measured 75us at 3 GB/s (R11 counters) - custom kernel is ~2us.
  k_zero<<<104, 256, 0, stream>>>(CmAcc, 26624);
  k_wsplit3<<<128, 256, 0, stream>>>(W, Wh, Wm, Wl);
  k_gemm<<<512, 256, 0, stream>>>(x, Wh, Wm, Wl, Lpart);
  k_post<<<256, 256, 0, stream>>>(Lpart, b, Lbuf, CmAcc);
  k_correct<<<256, 256, 0, stream>>>(Lbuf, CmAcc, M0buf, pAcc);
  for (int k = 1; k <= 9; k++)
    k_sink<<<256, 256, 0, stream>>>(M0buf, pAcc + (size_t)(k - 1) * 1024,
                                    pAcc + (size_t)k * 1024);
  k_final<<<256, 256, 0, stream>>>(M0buf, pAcc + (size_t)9 * 1024, pp, pmask, out);
}